// Round 8
// baseline (275.849 us; speedup 1.0000x reference)
//
#include <hip/hip_runtime.h>
#include <hip/hip_bf16.h>
#include <hip/hip_fp16.h>
#include <math.h>

#define N_TOK 2884
#define HW_IMG 576
#define NT_TOK 577
#define CDIM 768
#define NH 12
#define HD 64
#define QKV_COLS 2304
#define NVP 2944   // padded token stride for V^T planes (= 23*128)
#define NQT 46     // 64-row tiles (combine kernel)
#define NQB 23     // 128-row q blocks (attention)
#define NROWP 2944 // padded rows per head in Pacc

typedef float f32x4 __attribute__((ext_vector_type(4)));
typedef short bf16x8 __attribute__((ext_vector_type(8)));
typedef _Float16 f16x8 __attribute__((ext_vector_type(8)));
typedef unsigned short u16;
typedef unsigned short u16x8 __attribute__((ext_vector_type(8)));
typedef unsigned short u16x4 __attribute__((ext_vector_type(4)));

static __device__ __forceinline__ u16 f2bf(float f) {
    union { __hip_bfloat16 b; u16 u; } cv;
    cv.b = __float2bfloat16(f);
    return cv.u;
}
static __device__ __forceinline__ float bf2f(u16 h) {
    return __uint_as_float(((unsigned)h) << 16);
}
static __device__ __forceinline__ void split1(float f, u16& h, u16& l) {
    h = f2bf(f);
    l = f2bf(f - bf2f(h));
}
static __device__ __forceinline__ void split1h(float f, u16& h, u16& l) {
    const __half hh = __float2half(f);
    h = __half_as_ushort(hh);
    l = __half_as_ushort(__float2half(f - __half2float(hh)));
}
static __device__ __forceinline__ f16x8 as_f16x8(u16x8 u) {
    union { u16x8 u; f16x8 h; } c; c.u = u; return c.h;
}

// ---------------- conv_x ----------------
__global__ __launch_bounds__(256)
void conv_x(const float* __restrict__ q, const float* __restrict__ t,
            u16* __restrict__ Xhi, u16* __restrict__ Xlo)
{
    const int i = (blockIdx.x * 256 + threadIdx.x) * 4;
    const int SPLIT = HW_IMG * CDIM;
    const float4 v = (i < SPLIT) ? *(const float4*)(q + i) : *(const float4*)(t + (i - SPLIT));
    u16x4 h, l;
    u16 hh, ll;
    split1(v.x, hh, ll); h[0] = hh; l[0] = ll;
    split1(v.y, hh, ll); h[1] = hh; l[1] = ll;
    split1(v.z, hh, ll); h[2] = hh; l[2] = ll;
    split1(v.w, hh, ll); h[3] = hh; l[3] = ll;
    *(u16x4*)(Xhi + i) = h;
    *(u16x4*)(Xlo + i) = l;
}

// ---------------- conv_wT ----------------
__global__ __launch_bounds__(256)
void conv_wT(const float* __restrict__ W, int ncols,
             u16* __restrict__ Thi, u16* __restrict__ Tlo)
{
    __shared__ float T[64][65];
    const int k0 = blockIdx.x * 64;
    const int n0 = blockIdx.y * 64;
    const int tid = threadIdx.x;
    {
        const int kr = tid >> 2, nch = (tid & 3) << 4;
        const float* src = W + (size_t)(k0 + kr) * ncols + n0 + nch;
        #pragma unroll
        for (int c = 0; c < 4; ++c) {
            const float4 f = *(const float4*)(src + c * 4);
            T[kr][nch + c * 4 + 0] = f.x;
            T[kr][nch + c * 4 + 1] = f.y;
            T[kr][nch + c * 4 + 2] = f.z;
            T[kr][nch + c * 4 + 3] = f.w;
        }
    }
    __syncthreads();
    const int nr = tid >> 2, kch = (tid & 3) << 4;
    u16x8 h0, h1, l0v, l1v;
    #pragma unroll
    for (int j = 0; j < 8; ++j) { u16 hh, ll; split1(T[kch + j][nr], hh, ll); h0[j] = hh; l0v[j] = ll; }
    #pragma unroll
    for (int j = 0; j < 8; ++j) { u16 hh, ll; split1(T[kch + 8 + j][nr], hh, ll); h1[j] = hh; l1v[j] = ll; }
    const size_t dst = (size_t)(n0 + nr) * CDIM + k0 + kch;
    *(u16x8*)(Thi + dst) = h0;     *(u16x8*)(Thi + dst + 8) = h1;
    *(u16x8*)(Tlo + dst) = l0v;    *(u16x8*)(Tlo + dst + 8) = l1v;
}

// ---------------- Kernel 1: QKV via MFMA hi/lo, 128x64 tile ----------------
__global__ __launch_bounds__(256, 3)
void qkv_mfma(const u16* __restrict__ Xhi, const u16* __restrict__ Xlo,
              const u16* __restrict__ Whi, const u16* __restrict__ Wlo,
              const float* __restrict__ bqkv,
              const float* __restrict__ pos2d, const float* __restrict__ tposes,
              u16* __restrict__ Qhi, u16* __restrict__ Qlo,
              u16* __restrict__ Khi, u16* __restrict__ Klo,
              u16* __restrict__ Vthi, u16* __restrict__ Vtlo)
{
    __shared__ __align__(16) char smem[49152];
    u16 (*Ah)[64] = (u16(*)[64])(smem);
    u16 (*Al)[64] = (u16(*)[64])(smem + 16384);
    u16 (*Bh)[64] = (u16(*)[64])(smem + 32768);
    u16 (*Bl)[64] = (u16(*)[64])(smem + 40960);
    float (*Ct)[65] = (float(*)[65])(smem);

    const int rb = blockIdx.x;
    const int cb = blockIdx.y;
    const int which = cb / NH;
    const int h = cb - which * NH;
    const int colbase = cb * 64;
    const int tid = threadIdx.x;
    const int w = tid >> 6, l = tid & 63;
    const int lr = l & 15, lg = l >> 4;

    const int sa_r = tid >> 1;
    const int sa_c = (tid & 1) << 5;
    int arow = rb * 128 + sa_r;
    if (arow >= N_TOK) arow = N_TOK - 1;
    const size_t abase = (size_t)arow * CDIM + sa_c;
    const int swa_ = (sa_r & 7) << 3;
    const int sb_r = tid >> 2;
    const int sb_c = (tid & 3) << 4;
    const size_t bbase = (size_t)(colbase + sb_r) * CDIM + sb_c;
    const int swb_ = (sb_r & 7) << 3;

    const int swf = (lr & 7) << 3;

    f32x4 acc[2][4];
    #pragma unroll
    for (int rf = 0; rf < 2; ++rf)
        #pragma unroll
        for (int i = 0; i < 4; ++i) acc[rf][i] = (f32x4){0.f, 0.f, 0.f, 0.f};

    for (int k0 = 0; k0 < CDIM; k0 += 64) {
        u16x8 a_h[4], a_l[4], b_h[2], b_l[2];
        #pragma unroll
        for (int c = 0; c < 4; ++c) {
            a_h[c] = *(const u16x8*)(Xhi + abase + k0 + c * 8);
            a_l[c] = *(const u16x8*)(Xlo + abase + k0 + c * 8);
        }
        #pragma unroll
        for (int c = 0; c < 2; ++c) {
            b_h[c] = *(const u16x8*)(Whi + bbase + k0 + c * 8);
            b_l[c] = *(const u16x8*)(Wlo + bbase + k0 + c * 8);
        }
        __syncthreads();
        #pragma unroll
        for (int c = 0; c < 4; ++c) {
            *(u16x8*)&Ah[sa_r][(sa_c + c * 8) ^ swa_] = a_h[c];
            *(u16x8*)&Al[sa_r][(sa_c + c * 8) ^ swa_] = a_l[c];
        }
        #pragma unroll
        for (int c = 0; c < 2; ++c) {
            *(u16x8*)&Bh[sb_r][(sb_c + c * 8) ^ swb_] = b_h[c];
            *(u16x8*)&Bl[sb_r][(sb_c + c * 8) ^ swb_] = b_l[c];
        }
        __syncthreads();
        #pragma unroll
        for (int ks = 0; ks < 2; ++ks) {
            const int koff = (ks * 32 + lg * 8) ^ swf;
            const bf16x8 ah0 = *(const bf16x8*)&Ah[w * 32 + lr][koff];
            const bf16x8 al0 = *(const bf16x8*)&Al[w * 32 + lr][koff];
            const bf16x8 ah1 = *(const bf16x8*)&Ah[w * 32 + 16 + lr][koff];
            const bf16x8 al1 = *(const bf16x8*)&Al[w * 32 + 16 + lr][koff];
            #pragma unroll
            for (int cbk = 0; cbk < 4; ++cbk) {
                const bf16x8 bh_ = *(const bf16x8*)&Bh[cbk * 16 + lr][koff];
                const bf16x8 bl_ = *(const bf16x8*)&Bl[cbk * 16 + lr][koff];
                acc[0][cbk] = __builtin_amdgcn_mfma_f32_16x16x32_bf16(ah0, bh_, acc[0][cbk], 0, 0, 0);
                acc[0][cbk] = __builtin_amdgcn_mfma_f32_16x16x32_bf16(ah0, bl_, acc[0][cbk], 0, 0, 0);
                acc[0][cbk] = __builtin_amdgcn_mfma_f32_16x16x32_bf16(al0, bh_, acc[0][cbk], 0, 0, 0);
                acc[1][cbk] = __builtin_amdgcn_mfma_f32_16x16x32_bf16(ah1, bh_, acc[1][cbk], 0, 0, 0);
                acc[1][cbk] = __builtin_amdgcn_mfma_f32_16x16x32_bf16(ah1, bl_, acc[1][cbk], 0, 0, 0);
                acc[1][cbk] = __builtin_amdgcn_mfma_f32_16x16x32_bf16(al1, bh_, acc[1][cbk], 0, 0, 0);
            }
        }
    }

    __syncthreads();
    #pragma unroll
    for (int rf = 0; rf < 2; ++rf)
        #pragma unroll
        for (int cbk = 0; cbk < 4; ++cbk)
            #pragma unroll
            for (int r = 0; r < 4; ++r)
                Ct[w * 32 + rf * 16 + lg * 4 + r][cbk * 16 + lr] =
                    acc[rf][cbk][r] + bqkv[colbase + cbk * 16 + lr];
    __syncthreads();

    if (which < 2) {
        #pragma unroll
        for (int it = 0; it < 2; ++it) {
            const int item = it * 256 + tid;
            const int er = item >> 2;
            const int eu = item & 3;
            const int n = rb * 128 + er;
            if (n < N_TOK) {
                float outv[16];
                const bool is_img = (n < HW_IMG);
                int ts = 0, tj = 0;
                if (!is_img) { const int m = n - HW_IMG; ts = m / NT_TOK; tj = m - ts * NT_TOK; }

                if (is_img) {
                    const float p = (eu < 2) ? pos2d[2 * n] : pos2d[2 * n + 1];
                    const bool lowhalf = ((eu & 1) == 0);
                    #pragma unroll
                    for (int dd = 0; dd < 16; ++dd) {
                        const int d = (eu << 4) + dd;
                        float sv, cv;
                        sincosf(p * expf((float)dd * -0.28782313662425574f), &sv, &cv);
                        const float rot = lowhalf ? -Ct[er][d + 16] : Ct[er][d - 16];
                        outv[dd] = Ct[er][d] * cv + rot * sv;
                    }
                } else if (tj < HW_IMG) {
                    #pragma unroll
                    for (int dd = 0; dd < 16; ++dd) {
                        const int d = (eu << 4) + dd;
                        float val = Ct[er][d];
                        if (d < 30) {
                            const int g = d / 3;
                            const float* R = tposes + ts * 16 + (d - g * 3) * 4;
                            val = R[0] * Ct[er][g * 3] + R[1] * Ct[er][g * 3 + 1] + R[2] * Ct[er][g * 3 + 2];
                        }
                        outv[dd] = val;
                    }
                } else {
                    #pragma unroll
                    for (int dd = 0; dd < 16; ++dd) outv[dd] = Ct[er][(eu << 4) + dd];
                }

                const float scale = (which == 0) ? 0.125f : 1.0f;
                u16x8 h0, h1, l0v, l1v;
                #pragma unroll
                for (int j = 0; j < 8; ++j) { u16 hh, ll; split1(outv[j] * scale, hh, ll); h0[j] = hh; l0v[j] = ll; }
                #pragma unroll
                for (int j = 0; j < 8; ++j) { u16 hh, ll; split1(outv[8 + j] * scale, hh, ll); h1[j] = hh; l1v[j] = ll; }
                u16* dh = (which == 0 ? Qhi : Khi) + ((size_t)h * N_TOK + n) * HD + (eu << 4);
                u16* dl = (which == 0 ? Qlo : Klo) + ((size_t)h * N_TOK + n) * HD + (eu << 4);
                *(u16x8*)dh = h0;  *(u16x8*)(dh + 8) = h1;
                *(u16x8*)dl = l0v; *(u16x8*)(dl + 8) = l1v;
            }
        }
    } else {
        #pragma unroll
        for (int it = 0; it < 2; ++it) {
            const int item = it * 256 + tid;
            const int vd_ = item >> 3;
            const int vch = (item & 7) << 4;
            const int tokbase = rb * 128 + vch;
            u16 th[16], tl[16];
            #pragma unroll
            for (int j = 0; j < 16; ++j) { u16 hh, ll; split1h(Ct[vch + j][vd_], hh, ll); th[j] = hh; tl[j] = ll; }
            u16* dh = Vthi + (size_t)(h * HD + vd_) * NVP + tokbase;
            u16* dl = Vtlo + (size_t)(h * HD + vd_) * NVP + tokbase;
            if (tokbase + 16 <= N_TOK) {
                *(u16x8*)dh = *(u16x8*)&th[0];  *(u16x8*)(dh + 8) = *(u16x8*)&th[8];
                *(u16x8*)dl = *(u16x8*)&tl[0];  *(u16x8*)(dl + 8) = *(u16x8*)&tl[8];
            } else {
                #pragma unroll
                for (int j = 0; j < 16; ++j)
                    if (tokbase + j < N_TOK) { dh[j] = th[j]; dl[j] = tl[j]; }
            }
        }
    }
}

// ---------------- Kernel 2: split-K flash attention, 128 q-rows/block ----------------
// grid (23, 12, SPLITS) XCD-remapped. QK bf16 hi/lo; PV fp16. Reg-prefetch one tile ahead.
__global__ __launch_bounds__(256, 3)
void attn_shard(const u16* __restrict__ Qhi, const u16* __restrict__ Qlo,
                const u16* __restrict__ Khi, const u16* __restrict__ Klo,
                const u16* __restrict__ Vthi, const u16* __restrict__ Vtlo,
                float* __restrict__ Pacc, float2* __restrict__ PmL,
                int TS, int SPLITS)
{
    __shared__ __align__(16) u16 Kh_s[64][64], Kl_s[64][64];   // bf16 hi/lo (16 KB)
    __shared__ __align__(16) u16 Vh_s[64][64], Vl_s[64][64];   // fp16 hi/lo (16 KB)
    __shared__ __align__(16) u16 P2[128][64];                  // fp16 P, wave-private rows (16 KB)

    int qb, head, sh;
    {
        const int flat = blockIdx.x + NQB * (blockIdx.y + NH * blockIdx.z);
        if (SPLITS == 4) {
            const int grp = flat & 7;
            const int rest = flat >> 3;          // [0, 138)
            qb = rest % NQB;
            const int hs = grp + 8 * (rest / NQB);
            head = hs % NH;
            sh = hs / NH;
        } else {
            qb = blockIdx.x; head = blockIdx.y; sh = blockIdx.z;
        }
    }
    const int tid = threadIdx.x;
    const int w = tid >> 6, l = tid & 63;
    const int lr = l & 15, lg = l >> 4;

    const int kt_begin = sh * TS;
    const int kt_end = min(NQT, kt_begin + TS);

    // Q fragments: wave w owns rows w*32 .. w*32+31 (two 16-row fragments)
    bf16x8 qh_[2][2], ql_[2][2];
    #pragma unroll
    for (int rf = 0; rf < 2; ++rf) {
        int row = qb * 128 + w * 32 + rf * 16 + lr;
        if (row >= N_TOK) row = N_TOK - 1;
        const u16* qph = Qhi + ((size_t)head * N_TOK + row) * HD;
        const u16* qpl = Qlo + ((size_t)head * N_TOK + row) * HD;
        #pragma unroll
        for (int ks = 0; ks < 2; ++ks) {
            qh_[rf][ks] = *(const bf16x8*)(qph + ks * 32 + lg * 8);
            ql_[rf][ks] = *(const bf16x8*)(qpl + ks * 32 + lg * 8);
        }
    }

    float m0[2][4], l0[2][4];
    f32x4 acc[2][4];
    #pragma unroll
    for (int rf = 0; rf < 2; ++rf)
        #pragma unroll
        for (int r = 0; r < 4; ++r) {
            m0[rf][r] = -1e30f; l0[rf][r] = 0.f;
            acc[rf][r] = (f32x4){0.f, 0.f, 0.f, 0.f};
        }

    const int skey = tid >> 2, sch = (tid & 3) << 4;
    const int vd_ = tid >> 2, vch = (tid & 3) << 4;
    const int swk = (skey & 7) << 3;
    const int swv = (vd_ & 7) << 3;
    const int swf = (lr & 7) << 3;
    const u16* KhH = Khi + (size_t)head * N_TOK * HD;
    const u16* KlH = Klo + (size_t)head * N_TOK * HD;
    const size_t vrowbase = (size_t)(head * HD + vd_) * NVP;

    u16x8 rk0h, rk1h, rk0l, rk1l, rv0h, rv1h, rv0l, rv1l;
    auto LOADT = [&](int kt) {
        const int kbase = kt << 6;
        int krow = kbase + skey;
        if (krow >= N_TOK) krow = N_TOK - 1;
        const u16* kph = KhH + (size_t)krow * HD + sch;
        const u16* kpl = KlH + (size_t)krow * HD + sch;
        rk0h = *(const u16x8*)kph;  rk1h = *(const u16x8*)(kph + 8);
        rk0l = *(const u16x8*)kpl;  rk1l = *(const u16x8*)(kpl + 8);
        const u16* vph = Vthi + vrowbase + kbase + vch;
        const u16* vpl = Vtlo + vrowbase + kbase + vch;
        rv0h = *(const u16x8*)vph;  rv1h = *(const u16x8*)(vph + 8);
        rv0l = *(const u16x8*)vpl;  rv1l = *(const u16x8*)(vpl + 8);
    };
    LOADT(kt_begin);

    for (int kt = kt_begin; kt < kt_end; ++kt) {
        const int kbase = kt << 6;

        __syncthreads();
        *(u16x8*)&Kh_s[skey][(sch + 0) ^ swk] = rk0h;
        *(u16x8*)&Kh_s[skey][(sch + 8) ^ swk] = rk1h;
        *(u16x8*)&Kl_s[skey][(sch + 0) ^ swk] = rk0l;
        *(u16x8*)&Kl_s[skey][(sch + 8) ^ swk] = rk1l;
        *(u16x8*)&Vh_s[vd_][(vch + 0) ^ swv] = rv0h;
        *(u16x8*)&Vh_s[vd_][(vch + 8) ^ swv] = rv1h;
        *(u16x8*)&Vl_s[vd_][(vch + 0) ^ swv] = rv0l;
        *(u16x8*)&Vl_s[vd_][(vch + 8) ^ swv] = rv1l;
        if (kt + 1 < kt_end) LOADT(kt + 1);
        __syncthreads();

        // ---- S = Q K^T for both row-fragments (shared K frag reads) ----
        f32x4 s[2][4];
        __builtin_amdgcn_s_setprio(1);
        #pragma unroll
        for (int kb = 0; kb < 4; ++kb) {
            s[0][kb] = (f32x4){0.f, 0.f, 0.f, 0.f};
            s[1][kb] = (f32x4){0.f, 0.f, 0.f, 0.f};
            const int key = kb * 16 + lr;
            #pragma unroll
            for (int ks = 0; ks < 2; ++ks) {
                const int koff = (ks * 32 + lg * 8) ^ swf;
                const bf16x8 bh = *(const bf16x8*)&Kh_s[key][koff];
                const bf16x8 bl = *(const bf16x8*)&Kl_s[key][koff];
                s[0][kb] = __builtin_amdgcn_mfma_f32_16x16x32_bf16(qh_[0][ks], bh, s[0][kb], 0, 0, 0);
                s[0][kb] = __builtin_amdgcn_mfma_f32_16x16x32_bf16(qh_[0][ks], bl, s[0][kb], 0, 0, 0);
                s[0][kb] = __builtin_amdgcn_mfma_f32_16x16x32_bf16(ql_[0][ks], bh, s[0][kb], 0, 0, 0);
                s[1][kb] = __builtin_amdgcn_mfma_f32_16x16x32_bf16(qh_[1][ks], bh, s[1][kb], 0, 0, 0);
                s[1][kb] = __builtin_amdgcn_mfma_f32_16x16x32_bf16(qh_[1][ks], bl, s[1][kb], 0, 0, 0);
                s[1][kb] = __builtin_amdgcn_mfma_f32_16x16x32_bf16(ql_[1][ks], bh, s[1][kb], 0, 0, 0);
            }
        }
        __builtin_amdgcn_s_setprio(0);

        if (kbase + 64 > N_TOK) {
            #pragma unroll
            for (int kb = 0; kb < 4; ++kb)
                if (kbase + kb * 16 + lr >= N_TOK) {
                    #pragma unroll
                    for (int r = 0; r < 4; ++r) { s[0][kb][r] = -1e30f; s[1][kb][r] = -1e30f; }
                }
        }

        // ---- online softmax + P pack per row-fragment ----
        #pragma unroll
        for (int rf = 0; rf < 2; ++rf) {
            float mt[4], al[4];
            #pragma unroll
            for (int r = 0; r < 4; ++r)
                mt[r] = fmaxf(fmaxf(s[rf][0][r], s[rf][1][r]), fmaxf(s[rf][2][r], s[rf][3][r]));
            #pragma unroll
            for (int r = 0; r < 4; ++r) {
                mt[r] = fmaxf(mt[r], __shfl_xor(mt[r], 1));
                mt[r] = fmaxf(mt[r], __shfl_xor(mt[r], 2));
                mt[r] = fmaxf(mt[r], __shfl_xor(mt[r], 4));
                mt[r] = fmaxf(mt[r], __shfl_xor(mt[r], 8));
            }
            #pragma unroll
            for (int r = 0; r < 4; ++r) {
                const float mn = fmaxf(m0[rf][r], mt[r]);
                al[r] = __expf(m0[rf][r] - mn);
                m0[rf][r] = mn;
            }
            #pragma unroll
            for (int kb = 0; kb < 4; ++kb)
                #pragma unroll
                for (int r = 0; r < 4; ++r)
                    s[rf][kb][r] = __expf(s[rf][kb][r] - m0[rf][r]);
            #pragma unroll
            for (int r = 0; r < 4; ++r)
                l0[rf][r] = l0[rf][r] * al[r] + (s[rf][0][r] + s[rf][1][r] + s[rf][2][r] + s[rf][3][r]);
            #pragma unroll
            for (int db = 0; db < 4; ++db)
                #pragma unroll
                for (int r = 0; r < 4; ++r) acc[rf][db][r] *= al[r];

            #pragma unroll
            for (int r = 0; r < 4; ++r) {
                const int rw = w * 32 + rf * 16 + lg * 4 + r;
                const int swp = (rw & 7) << 3;
                #pragma unroll
                for (int kb = 0; kb < 4; ++kb)
                    P2[rw][(kb * 16 + lr) ^ swp] = __half_as_ushort(__float2half(s[rf][kb][r]));
            }
        }

        // ---- PV for both row-fragments (shared V frag reads) ----
        const int ar0 = w * 32 + lr;
        const int ar1 = w * 32 + 16 + lr;
        const int sw0 = (ar0 & 7) << 3;
        const int sw1 = (ar1 & 7) << 3;
        #pragma unroll
        for (int ks = 0; ks < 2; ++ks) {
            const int kb8 = ks * 32 + lg * 8;
            const f16x8 pa0 = as_f16x8(*(const u16x8*)&P2[ar0][kb8 ^ sw0]);
            const f16x8 pa1 = as_f16x8(*(const u16x8*)&P2[ar1][kb8 ^ sw1]);
            __builtin_amdgcn_s_setprio(1);
            #pragma unroll
            for (int db = 0; db < 4; ++db) {
                const int vr = db * 16 + lr;
                const int koff = kb8 ^ swf;
                const f16x8 vh = as_f16x8(*(const u16x8*)&Vh_s[vr][koff]);
                const f16x8 vl = as_f16x8(*(const u16x8*)&Vl_s[vr][koff]);
                acc[0][db] = __builtin_amdgcn_mfma_f32_16x16x32_f16(pa0, vh, acc[0][db], 0, 0, 0);
                acc[0][db] = __builtin_amdgcn_mfma_f32_16x16x32_f16(pa0, vl, acc[0][db], 0, 0, 0);
                acc[1][db] = __builtin_amdgcn_mfma_f32_16x16x32_f16(pa1, vh, acc[1][db], 0, 0, 0);
                acc[1][db] = __builtin_amdgcn_mfma_f32_16x16x32_f16(pa1, vl, acc[1][db], 0, 0, 0);
            }
            __builtin_amdgcn_s_setprio(0);
        }
    }

    // ---- epilogue: reduce row sums, store unnormalized partials ----
    #pragma unroll
    for (int rf = 0; rf < 2; ++rf)
        #pragma unroll
        for (int r = 0; r < 4; ++r) {
            l0[rf][r] += __shfl_xor(l0[rf][r], 1);
            l0[rf][r] += __shfl_xor(l0[rf][r], 2);
            l0[rf][r] += __shfl_xor(l0[rf][r], 4);
            l0[rf][r] += __shfl_xor(l0[rf][r], 8);
        }
    const size_t rowbase = (size_t)(sh * NH + head) * NROWP + qb * 128;
    #pragma unroll
    for (int rf = 0; rf < 2; ++rf)
        #pragma unroll
        for (int r = 0; r < 4; ++r) {
            const int lrow = w * 32 + rf * 16 + lg * 4 + r;
            float* pout = Pacc + (rowbase + lrow) * 64;
            #pragma unroll
            for (int db = 0; db < 4; ++db)
                pout[db * 16 + lr] = acc[rf][db][r];
            if (lr == 0)
                PmL[rowbase + lrow] = make_float2(m0[rf][r], l0[rf][r]);
        }
}

// ---------------- Kernel 2b: combine shards ----------------
__global__ __launch_bounds__(256)
void attn_combine(const float* __restrict__ Pacc, const float2* __restrict__ PmL,
                  u16* __restrict__ Ohi, u16* __restrict__ Olo, int SPLITS)
{
    const int qb = blockIdx.x, h = blockIdx.y;
    const int tid = threadIdx.x;
    const int er = tid >> 2, eu = tid & 3;
    const int row = qb * 64 + er;
    if (row >= N_TOK) return;

    float ms[4], ls[4];
    float m = -1e30f;
    for (int s = 0; s < SPLITS; ++s) {
        const float2 p = PmL[(size_t)(s * NH + h) * NROWP + row];
        ms[s] = p.x; ls[s] = p.y;
        m = fmaxf(m, p.x);
    }
    float L = 0.f, Ws[4];
    for (int s = 0; s < SPLITS; ++s) { Ws[s] = __expf(ms[s] - m); L += ls[s] * Ws[s]; }
    const float inv = 1.f / L;

    float o[16];
    #pragma unroll
    for (int j = 0; j < 16; ++j) o[j] = 0.f;
    for (int s = 0; s < SPLITS; ++s) {
        const float* src = Pacc + ((size_t)(s * NH + h) * NROWP + row) * 64 + (eu << 4);
        const float wgt = Ws[s];
        #pragma unroll
        for (int c = 0; c < 4; ++c) {
            const float4 f = *(const float4*)(src + c * 4);
            o[c * 4 + 0] += wgt * f.x;
            o[c * 4 + 1] += wgt * f.y;
            o[c * 4 + 2] += wgt * f.z;
            o[c * 4 + 3] += wgt * f.w;
        }
    }
    u16x8 h0, h1, l0v, l1v;
    #pragma unroll
    for (int j = 0; j < 8; ++j) { u16 hh, ll; split1(o[j] * inv, hh, ll); h0[j] = hh; l0v[j] = ll; }
    #pragma unroll
    for (int j = 0; j < 8; ++j) { u16 hh, ll; split1(o[8 + j] * inv, hh, ll); h1[j] = hh; l1v[j] = ll; }
    u16* dh = Ohi + (size_t)row * CDIM + h * HD + (eu << 4);
    u16* dl = Olo + (size_t)row * CDIM + h * HD + (eu << 4);
    *(u16x8*)dh = h0;  *(u16x8*)(dh + 8) = h1;
    *(u16x8*)dl = l0v; *(u16x8*)(dl + 8) = l1v;
}

// ---------------- Kernel 3: output projection via MFMA hi/lo ----------------
__global__ __launch_bounds__(256)
void proj_mfma(const u16* __restrict__ Ahi, const u16* __restrict__ Alo,
               const u16* __restrict__ Whi, const u16* __restrict__ Wlo,
               const float* __restrict__ bp, float* __restrict__ out)
{
    __shared__ __align__(16) u16 Ah[64][64], Al[64][64], Bh[64][64], Bl[64][64];

    const int rb = blockIdx.x;
    const int colbase = blockIdx.y * 64;
    const int tid = threadIdx.x;
    const int w = tid >> 6, l = tid & 63;
    const int lr = l & 15, lg = l >> 4;

    const int srow = tid >> 2, sch = (tid & 3) << 4;
    int arow = rb * 64 + srow;
    if (arow >= N_TOK) arow = N_TOK - 1;
    const size_t abase = (size_t)arow * CDIM + sch;
    const size_t bbase = (size_t)(colbase + srow) * CDIM + sch;

    f32x4 acc[4];
    #pragma unroll
    for (int i = 0; i < 4; ++i) acc[i] = (f32x4){0.f, 0.f, 0.f, 0.f};

    const int sw = (srow & 7) << 3;
    const int swf = (lr & 7) << 3;

    for (int k0 = 0; k0 < CDIM; k0 += 64) {
        const u16x8 a0h = *(const u16x8*)(Ahi + abase + k0);
        const u16x8 a1h = *(const u16x8*)(Ahi + abase + k0 + 8);
        const u16x8 a0l = *(const u16x8*)(Alo + abase + k0);
        const u16x8 a1l = *(const u16x8*)(Alo + abase + k0 + 8);
        const u16x8 b0h = *(const u16x8*)(Whi + bbase + k0);
        const u16x8 b1h = *(const u16x8*)(Whi + bbase + k0 + 8);
        const u16x8 b0l = *(const u16x8*)(Wlo + bbase + k0);
        const u16x8 b1l = *(const u16x8*)(Wlo + bbase + k0 + 8);
        __syncthreads();
        *(u16x8*)&Ah[srow][(sch + 0) ^ sw] = a0h;
        *(u16x8*)&Ah[srow][(sch + 8) ^ sw] = a1h;
        *(u16x8*)&Al[srow][(sch + 0) ^ sw] = a0l;
        *(u16x8*)&Al[srow][(sch + 8) ^ sw] = a1l;
        *(u16x8*)&Bh[srow][(sch + 0) ^ sw] = b0h;
        *(u16x8*)&Bh[srow][(sch + 8) ^ sw] = b1h;
        *(u16x8*)&Bl[srow][(sch + 0) ^ sw] = b0l;
        *(u16x8*)&Bl[srow][(sch + 8) ^ sw] = b1l;
        __syncthreads();
        #pragma unroll
        for (int ks = 0; ks < 2; ++ks) {
            const int koff = (ks * 32 + lg * 8) ^ swf;
            const bf16x8 ah_ = *(const bf16x8*)&Ah[w * 16 + lr][koff];
            const bf16x8 al_ = *(const bf16x8*)&Al[w * 16 + lr][koff];
            #pragma unroll
            for (int cbk = 0; cbk < 4; ++cbk) {
                const bf16x8 bh_ = *(const bf16x8*)&Bh[cbk * 16 + lr][koff];
                const bf16x8 bl_ = *(const bf16x8*)&Bl[cbk * 16 + lr][koff];
                acc[cbk] = __builtin_amdgcn_mfma_f32_16x16x32_bf16(ah_, bh_, acc[cbk], 0, 0, 0);
                acc[cbk] = __builtin_amdgcn_mfma_f32_16x16x32_bf16(ah_, bl_, acc[cbk], 0, 0, 0);
                acc[cbk] = __builtin_amdgcn_mfma_f32_16x16x32_bf16(al_, bh_, acc[cbk], 0, 0, 0);
            }
        }
    }

    #pragma unroll
    for (int cbk = 0; cbk < 4; ++cbk) {
        const float bb = bp[colbase + cbk * 16 + lr];
        #pragma unroll
        for (int r = 0; r < 4; ++r) {
            const int row = rb * 64 + w * 16 + lg * 4 + r;
            if (row < N_TOK)
                out[(size_t)row * CDIM + colbase + cbk * 16 + lr] = acc[cbk][r] + bb;
        }
    }
}

extern "C" void kernel_launch(void* const* d_in, const int* in_sizes, int n_in,
                              void* d_out, int out_size, void* d_ws, size_t ws_size,
                              hipStream_t stream)
{
    const float* q_tokens = (const float*)d_in[0];
    const float* t_tokens = (const float*)d_in[1];
    const float* pos2d    = (const float*)d_in[2];
    const float* tposes   = (const float*)d_in[3];
    const float* Wqkv     = (const float*)d_in[4];
    const float* bqkv     = (const float*)d_in[5];
    const float* Wproj    = (const float*)d_in[6];
    const float* bproj    = (const float*)d_in[7];
    float* out = (float*)d_out;

    const size_t PQ = (size_t)NH * N_TOK * HD;
    const size_t PV_ = (size_t)NH * HD * NVP;
    const size_t PX = (size_t)N_TOK * CDIM;
    const size_t PW = (size_t)QKV_COLS * CDIM;

    u16* base = (u16*)d_ws;
    u16* Qhi  = base;
    u16* Qlo  = Qhi + PQ;
    u16* Khi  = Qlo + PQ;
    u16* Klo  = Khi + PQ;
    u16* Vthi = Klo + PQ;
    u16* Vtlo = Vthi + PV_;
    u16* XOhi = Vtlo + PV_;
    u16* XOlo = XOhi + PX;
    u16* WThi = XOlo + PX;
    u16* WTlo = WThi + PW;
    u16* planes_end = WTlo + PW;

    const size_t planes_bytes = (size_t)(planes_end - base) * sizeof(u16);
    const size_t accElems = (size_t)NH * NROWP * 64;   // per-shard Pacc floats
    const size_t mlElems  = (size_t)NH * NROWP;        // per-shard PmL float2s
    const size_t per_shard = accElems * 4 + mlElems * 8;

    int SPLITS = 1;
    for (int cand = 4; cand >= 2; --cand) {
        if (planes_bytes + (size_t)cand * per_shard <= ws_size) { SPLITS = cand; break; }
    }
    float* Pacc = (float*)((char*)d_ws + planes_bytes);
    float2* PmL = (float2*)(Pacc + (size_t)SPLITS * accElems);
    const int TS = (NQT + SPLITS - 1) / SPLITS;

    conv_x<<<dim3((N_TOK * CDIM / 4 + 255) / 256), 256, 0, stream>>>(q_tokens, t_tokens, XOhi, XOlo);
    conv_wT<<<dim3(CDIM / 64, QKV_COLS / 64), 256, 0, stream>>>(Wqkv, QKV_COLS, WThi, WTlo);
    hipMemsetAsync(Vthi, 0, 2 * PV_ * sizeof(u16), stream);

    dim3 g1((N_TOK + 127) / 128, 36);
    qkv_mfma<<<g1, 256, 0, stream>>>(XOhi, XOlo, WThi, WTlo, bqkv, pos2d, tposes,
                                     Qhi, Qlo, Khi, Klo, Vthi, Vtlo);

    conv_wT<<<dim3(CDIM / 64, CDIM / 64), 256, 0, stream>>>(Wproj, CDIM, WThi, WTlo);

    dim3 g2(NQB, NH, SPLITS);
    attn_shard<<<g2, 256, 0, stream>>>(Qhi, Qlo, Khi, Klo, Vthi, Vtlo, Pacc, PmL, TS, SPLITS);

    dim3 g2b(NQT, NH);
    attn_combine<<<g2b, 256, 0, stream>>>(Pacc, PmL, XOhi, XOlo, SPLITS);

    dim3 g3((N_TOK + 63) / 64, CDIM / 64);
    proj_mfma<<<g3, 256, 0, stream>>>(XOhi, XOlo, WThi, WTlo, bproj, out);
}

// Round 9
// 218.224 us; speedup vs baseline: 1.2641x; 1.2641x over previous
//
#include <hip/hip_runtime.h>
#include <hip/hip_bf16.h>
#include <hip/hip_fp16.h>
#include <math.h>

#define N_TOK 2884
#define HW_IMG 576
#define NT_TOK 577
#define CDIM 768
#define NH 12
#define HD 64
#define QKV_COLS 2304
#define NVP 2944   // padded token stride for V^T planes
#define NQT 46     // number of 64-row q tiles (attention)

typedef float f32x4 __attribute__((ext_vector_type(4)));
typedef short bf16x8 __attribute__((ext_vector_type(8)));
typedef _Float16 f16x8 __attribute__((ext_vector_type(8)));
typedef unsigned short u16;
typedef unsigned short u16x8 __attribute__((ext_vector_type(8)));
typedef unsigned short u16x4 __attribute__((ext_vector_type(4)));

static __device__ __forceinline__ u16 f2bf(float f) {
    union { __hip_bfloat16 b; u16 u; } cv;
    cv.b = __float2bfloat16(f);
    return cv.u;
}
static __device__ __forceinline__ float bf2f(u16 h) {
    return __uint_as_float(((unsigned)h) << 16);
}
static __device__ __forceinline__ void split1(float f, u16& h, u16& l) {
    h = f2bf(f);
    l = f2bf(f - bf2f(h));
}
// fp16 hi/lo split (for V planes)
static __device__ __forceinline__ void split1h(float f, u16& h, u16& l) {
    const __half hh = __float2half(f);
    h = __half_as_ushort(hh);
    l = __half_as_ushort(__float2half(f - __half2float(hh)));
}
static __device__ __forceinline__ f16x8 as_f16x8(u16x8 u) {
    union { u16x8 u; f16x8 h; } c; c.u = u; return c.h;
}

// ---------------- conv_x ----------------
__global__ __launch_bounds__(256)
void conv_x(const float* __restrict__ q, const float* __restrict__ t,
            u16* __restrict__ Xhi, u16* __restrict__ Xlo)
{
    const int i = (blockIdx.x * 256 + threadIdx.x) * 4;
    const int SPLIT = HW_IMG * CDIM;
    const float4 v = (i < SPLIT) ? *(const float4*)(q + i) : *(const float4*)(t + (i - SPLIT));
    u16x4 h, l;
    u16 hh, ll;
    split1(v.x, hh, ll); h[0] = hh; l[0] = ll;
    split1(v.y, hh, ll); h[1] = hh; l[1] = ll;
    split1(v.z, hh, ll); h[2] = hh; l[2] = ll;
    split1(v.w, hh, ll); h[3] = hh; l[3] = ll;
    *(u16x4*)(Xhi + i) = h;
    *(u16x4*)(Xlo + i) = l;
}

// ---------------- conv_wT ----------------
__global__ __launch_bounds__(256)
void conv_wT(const float* __restrict__ W, int ncols,
             u16* __restrict__ Thi, u16* __restrict__ Tlo)
{
    __shared__ float T[64][65];
    const int k0 = blockIdx.x * 64;
    const int n0 = blockIdx.y * 64;
    const int tid = threadIdx.x;
    {
        const int kr = tid >> 2, nch = (tid & 3) << 4;
        const float* src = W + (size_t)(k0 + kr) * ncols + n0 + nch;
        #pragma unroll
        for (int c = 0; c < 4; ++c) {
            const float4 f = *(const float4*)(src + c * 4);
            T[kr][nch + c * 4 + 0] = f.x;
            T[kr][nch + c * 4 + 1] = f.y;
            T[kr][nch + c * 4 + 2] = f.z;
            T[kr][nch + c * 4 + 3] = f.w;
        }
    }
    __syncthreads();
    const int nr = tid >> 2, kch = (tid & 3) << 4;
    u16x8 h0, h1, l0v, l1v;
    #pragma unroll
    for (int j = 0; j < 8; ++j) { u16 hh, ll; split1(T[kch + j][nr], hh, ll); h0[j] = hh; l0v[j] = ll; }
    #pragma unroll
    for (int j = 0; j < 8; ++j) { u16 hh, ll; split1(T[kch + 8 + j][nr], hh, ll); h1[j] = hh; l1v[j] = ll; }
    const size_t dst = (size_t)(n0 + nr) * CDIM + k0 + kch;
    *(u16x8*)(Thi + dst) = h0;     *(u16x8*)(Thi + dst + 8) = h1;
    *(u16x8*)(Tlo + dst) = l0v;    *(u16x8*)(Tlo + dst + 8) = l1v;
}

// ---------------- Kernel 1: QKV via MFMA hi/lo, 128x64 tile ----------------
__global__ __launch_bounds__(256, 3)
void qkv_mfma(const u16* __restrict__ Xhi, const u16* __restrict__ Xlo,
              const u16* __restrict__ Whi, const u16* __restrict__ Wlo,
              const float* __restrict__ bqkv,
              const float* __restrict__ pos2d, const float* __restrict__ tposes,
              u16* __restrict__ Qhi, u16* __restrict__ Qlo,
              u16* __restrict__ Khi, u16* __restrict__ Klo,
              u16* __restrict__ Vthi, u16* __restrict__ Vtlo)
{
    __shared__ __align__(16) char smem[49152];
    u16 (*Ah)[64] = (u16(*)[64])(smem);
    u16 (*Al)[64] = (u16(*)[64])(smem + 16384);
    u16 (*Bh)[64] = (u16(*)[64])(smem + 32768);
    u16 (*Bl)[64] = (u16(*)[64])(smem + 40960);
    float (*Ct)[65] = (float(*)[65])(smem);

    const int rb = blockIdx.x;
    const int cb = blockIdx.y;
    const int which = cb / NH;
    const int h = cb - which * NH;
    const int colbase = cb * 64;
    const int tid = threadIdx.x;
    const int w = tid >> 6, l = tid & 63;
    const int lr = l & 15, lg = l >> 4;

    const int sa_r = tid >> 1;
    const int sa_c = (tid & 1) << 5;
    int arow = rb * 128 + sa_r;
    if (arow >= N_TOK) arow = N_TOK - 1;
    const size_t abase = (size_t)arow * CDIM + sa_c;
    const int swa_ = (sa_r & 7) << 3;
    const int sb_r = tid >> 2;
    const int sb_c = (tid & 3) << 4;
    const size_t bbase = (size_t)(colbase + sb_r) * CDIM + sb_c;
    const int swb_ = (sb_r & 7) << 3;

    const int swf = (lr & 7) << 3;

    f32x4 acc[2][4];
    #pragma unroll
    for (int rf = 0; rf < 2; ++rf)
        #pragma unroll
        for (int i = 0; i < 4; ++i) acc[rf][i] = (f32x4){0.f, 0.f, 0.f, 0.f};

    for (int k0 = 0; k0 < CDIM; k0 += 64) {
        u16x8 a_h[4], a_l[4], b_h[2], b_l[2];
        #pragma unroll
        for (int c = 0; c < 4; ++c) {
            a_h[c] = *(const u16x8*)(Xhi + abase + k0 + c * 8);
            a_l[c] = *(const u16x8*)(Xlo + abase + k0 + c * 8);
        }
        #pragma unroll
        for (int c = 0; c < 2; ++c) {
            b_h[c] = *(const u16x8*)(Whi + bbase + k0 + c * 8);
            b_l[c] = *(const u16x8*)(Wlo + bbase + k0 + c * 8);
        }
        __syncthreads();
        #pragma unroll
        for (int c = 0; c < 4; ++c) {
            *(u16x8*)&Ah[sa_r][(sa_c + c * 8) ^ swa_] = a_h[c];
            *(u16x8*)&Al[sa_r][(sa_c + c * 8) ^ swa_] = a_l[c];
        }
        #pragma unroll
        for (int c = 0; c < 2; ++c) {
            *(u16x8*)&Bh[sb_r][(sb_c + c * 8) ^ swb_] = b_h[c];
            *(u16x8*)&Bl[sb_r][(sb_c + c * 8) ^ swb_] = b_l[c];
        }
        __syncthreads();
        #pragma unroll
        for (int ks = 0; ks < 2; ++ks) {
            const int koff = (ks * 32 + lg * 8) ^ swf;
            const bf16x8 ah0 = *(const bf16x8*)&Ah[w * 32 + lr][koff];
            const bf16x8 al0 = *(const bf16x8*)&Al[w * 32 + lr][koff];
            const bf16x8 ah1 = *(const bf16x8*)&Ah[w * 32 + 16 + lr][koff];
            const bf16x8 al1 = *(const bf16x8*)&Al[w * 32 + 16 + lr][koff];
            #pragma unroll
            for (int cbk = 0; cbk < 4; ++cbk) {
                const bf16x8 bh_ = *(const bf16x8*)&Bh[cbk * 16 + lr][koff];
                const bf16x8 bl_ = *(const bf16x8*)&Bl[cbk * 16 + lr][koff];
                acc[0][cbk] = __builtin_amdgcn_mfma_f32_16x16x32_bf16(ah0, bh_, acc[0][cbk], 0, 0, 0);
                acc[0][cbk] = __builtin_amdgcn_mfma_f32_16x16x32_bf16(ah0, bl_, acc[0][cbk], 0, 0, 0);
                acc[0][cbk] = __builtin_amdgcn_mfma_f32_16x16x32_bf16(al0, bh_, acc[0][cbk], 0, 0, 0);
                acc[1][cbk] = __builtin_amdgcn_mfma_f32_16x16x32_bf16(ah1, bh_, acc[1][cbk], 0, 0, 0);
                acc[1][cbk] = __builtin_amdgcn_mfma_f32_16x16x32_bf16(ah1, bl_, acc[1][cbk], 0, 0, 0);
                acc[1][cbk] = __builtin_amdgcn_mfma_f32_16x16x32_bf16(al1, bh_, acc[1][cbk], 0, 0, 0);
            }
        }
    }

    __syncthreads();
    #pragma unroll
    for (int rf = 0; rf < 2; ++rf)
        #pragma unroll
        for (int cbk = 0; cbk < 4; ++cbk)
            #pragma unroll
            for (int r = 0; r < 4; ++r)
                Ct[w * 32 + rf * 16 + lg * 4 + r][cbk * 16 + lr] =
                    acc[rf][cbk][r] + bqkv[colbase + cbk * 16 + lr];
    __syncthreads();

    if (which < 2) {
        #pragma unroll
        for (int it = 0; it < 2; ++it) {
            const int item = it * 256 + tid;
            const int er = item >> 2;
            const int eu = item & 3;
            const int n = rb * 128 + er;
            if (n < N_TOK) {
                float outv[16];
                const bool is_img = (n < HW_IMG);
                int ts = 0, tj = 0;
                if (!is_img) { const int m = n - HW_IMG; ts = m / NT_TOK; tj = m - ts * NT_TOK; }

                if (is_img) {
                    const float p = (eu < 2) ? pos2d[2 * n] : pos2d[2 * n + 1];
                    const bool lowhalf = ((eu & 1) == 0);
                    #pragma unroll
                    for (int dd = 0; dd < 16; ++dd) {
                        const int d = (eu << 4) + dd;
                        float sv, cv;
                        sincosf(p * expf((float)dd * -0.28782313662425574f), &sv, &cv);
                        const float rot = lowhalf ? -Ct[er][d + 16] : Ct[er][d - 16];
                        outv[dd] = Ct[er][d] * cv + rot * sv;
                    }
                } else if (tj < HW_IMG) {
                    #pragma unroll
                    for (int dd = 0; dd < 16; ++dd) {
                        const int d = (eu << 4) + dd;
                        float val = Ct[er][d];
                        if (d < 30) {
                            const int g = d / 3;
                            const float* R = tposes + ts * 16 + (d - g * 3) * 4;
                            val = R[0] * Ct[er][g * 3] + R[1] * Ct[er][g * 3 + 1] + R[2] * Ct[er][g * 3 + 2];
                        }
                        outv[dd] = val;
                    }
                } else {
                    #pragma unroll
                    for (int dd = 0; dd < 16; ++dd) outv[dd] = Ct[er][(eu << 4) + dd];
                }

                const float scale = (which == 0) ? 0.125f : 1.0f;
                u16x8 h0, h1, l0v, l1v;
                #pragma unroll
                for (int j = 0; j < 8; ++j) { u16 hh, ll; split1(outv[j] * scale, hh, ll); h0[j] = hh; l0v[j] = ll; }
                #pragma unroll
                for (int j = 0; j < 8; ++j) { u16 hh, ll; split1(outv[8 + j] * scale, hh, ll); h1[j] = hh; l1v[j] = ll; }
                u16* dh = (which == 0 ? Qhi : Khi) + ((size_t)h * N_TOK + n) * HD + (eu << 4);
                u16* dl = (which == 0 ? Qlo : Klo) + ((size_t)h * N_TOK + n) * HD + (eu << 4);
                *(u16x8*)dh = h0;  *(u16x8*)(dh + 8) = h1;
                *(u16x8*)dl = l0v; *(u16x8*)(dl + 8) = l1v;
            }
        }
    } else {
        #pragma unroll
        for (int it = 0; it < 2; ++it) {
            const int item = it * 256 + tid;
            const int vd_ = item >> 3;
            const int vch = (item & 7) << 4;
            const int tokbase = rb * 128 + vch;
            u16 th[16], tl[16];
            #pragma unroll
            for (int j = 0; j < 16; ++j) { u16 hh, ll; split1h(Ct[vch + j][vd_], hh, ll); th[j] = hh; tl[j] = ll; }
            u16* dh = Vthi + (size_t)(h * HD + vd_) * NVP + tokbase;
            u16* dl = Vtlo + (size_t)(h * HD + vd_) * NVP + tokbase;
            if (tokbase + 16 <= N_TOK) {
                *(u16x8*)dh = *(u16x8*)&th[0];  *(u16x8*)(dh + 8) = *(u16x8*)&th[8];
                *(u16x8*)dl = *(u16x8*)&tl[0];  *(u16x8*)(dl + 8) = *(u16x8*)&tl[8];
            } else {
                #pragma unroll
                for (int j = 0; j < 16; ++j)
                    if (tokbase + j < N_TOK) { dh[j] = th[j]; dl[j] = tl[j]; }
            }
        }
    }
}

// ---------------- Kernel 2: split-K flash attention; QK bf16 hi/lo, PV fp16 ----------------
// 64 q-rows/block, reg-prefetch one tile ahead, 2 barriers/tile, wave-private P.
// launch_bounds (256,3): ~170-VGPR budget -> NO spill (R7/R8 regression was spill at 64/84 VGPR).
__global__ __launch_bounds__(256, 3)
void attn_shard(const u16* __restrict__ Qhi, const u16* __restrict__ Qlo,
                const u16* __restrict__ Khi, const u16* __restrict__ Klo,
                const u16* __restrict__ Vthi, const u16* __restrict__ Vtlo,
                float* __restrict__ Pacc, float2* __restrict__ PmL,
                int TS, int SPLITS)
{
    __shared__ __align__(16) u16 Kh_s[64][64], Kl_s[64][64];   // bf16 hi/lo
    __shared__ __align__(16) u16 Vh_s[64][64], Vl_s[64][64];   // fp16 hi/lo
    __shared__ __align__(16) u16 P2[64][64];                   // fp16 P (wave-private rows)

    int qb, head, sh;
    {
        const int flat = blockIdx.x + NQT * (blockIdx.y + NH * blockIdx.z);
        if (SPLITS == 4) {
            const int grp = flat & 7;
            const int rest = flat >> 3;
            qb = rest % NQT;
            const int hs = grp + 8 * (rest / NQT);
            head = hs % NH;
            sh = hs / NH;
        } else {
            qb = blockIdx.x; head = blockIdx.y; sh = blockIdx.z;
        }
    }
    const int tid = threadIdx.x;
    const int w = tid >> 6, l = tid & 63;
    const int lr = l & 15, lg = l >> 4;

    const int kt_begin = sh * TS;
    const int kt_end = min(NQT, kt_begin + TS);

    bf16x8 qh_[2], ql_[2];
    {
        int row = qb * 64 + w * 16 + lr;
        if (row >= N_TOK) row = N_TOK - 1;
        const u16* qph = Qhi + ((size_t)head * N_TOK + row) * HD;
        const u16* qpl = Qlo + ((size_t)head * N_TOK + row) * HD;
        #pragma unroll
        for (int ks = 0; ks < 2; ++ks) {
            qh_[ks] = *(const bf16x8*)(qph + ks * 32 + lg * 8);
            ql_[ks] = *(const bf16x8*)(qpl + ks * 32 + lg * 8);
        }
    }

    float m0[4] = {-1e30f, -1e30f, -1e30f, -1e30f};
    float l0[4] = {0.f, 0.f, 0.f, 0.f};
    f32x4 acc[4];
    #pragma unroll
    for (int db = 0; db < 4; ++db) acc[db] = (f32x4){0.f, 0.f, 0.f, 0.f};

    const int skey = tid >> 2, sch = (tid & 3) << 4;
    const int vd_ = tid >> 2, vch = (tid & 3) << 4;
    const int swk = (skey & 7) << 3;
    const int swv = (vd_ & 7) << 3;
    const int swf = (lr & 7) << 3;
    const u16* KhH = Khi + (size_t)head * N_TOK * HD;
    const u16* KlH = Klo + (size_t)head * N_TOK * HD;
    const size_t vrowbase = (size_t)(head * HD + vd_) * NVP;

    u16x8 rk0h, rk1h, rk0l, rk1l, rv0h, rv1h, rv0l, rv1l;
    auto LOADT = [&](int kt) {
        const int kbase = kt << 6;
        int krow = kbase + skey;
        if (krow >= N_TOK) krow = N_TOK - 1;
        const u16* kph = KhH + (size_t)krow * HD + sch;
        const u16* kpl = KlH + (size_t)krow * HD + sch;
        rk0h = *(const u16x8*)kph;  rk1h = *(const u16x8*)(kph + 8);
        rk0l = *(const u16x8*)kpl;  rk1l = *(const u16x8*)(kpl + 8);
        const u16* vph = Vthi + vrowbase + kbase + vch;
        const u16* vpl = Vtlo + vrowbase + kbase + vch;
        rv0h = *(const u16x8*)vph;  rv1h = *(const u16x8*)(vph + 8);
        rv0l = *(const u16x8*)vpl;  rv1l = *(const u16x8*)(vpl + 8);
    };
    LOADT(kt_begin);

    for (int kt = kt_begin; kt < kt_end; ++kt) {
        const int kbase = kt << 6;

        __syncthreads();
        *(u16x8*)&Kh_s[skey][(sch + 0) ^ swk] = rk0h;
        *(u16x8*)&Kh_s[skey][(sch + 8) ^ swk] = rk1h;
        *(u16x8*)&Kl_s[skey][(sch + 0) ^ swk] = rk0l;
        *(u16x8*)&Kl_s[skey][(sch + 8) ^ swk] = rk1l;
        *(u16x8*)&Vh_s[vd_][(vch + 0) ^ swv] = rv0h;
        *(u16x8*)&Vh_s[vd_][(vch + 8) ^ swv] = rv1h;
        *(u16x8*)&Vl_s[vd_][(vch + 0) ^ swv] = rv0l;
        *(u16x8*)&Vl_s[vd_][(vch + 8) ^ swv] = rv1l;
        if (kt + 1 < kt_end) LOADT(kt + 1);
        __syncthreads();

        // ---- S = Q K^T (bf16 hi/lo 3-product) ----
        f32x4 s[4];
        __builtin_amdgcn_s_setprio(1);
        #pragma unroll
        for (int kb = 0; kb < 4; ++kb) {
            s[kb] = (f32x4){0.f, 0.f, 0.f, 0.f};
            const int key = kb * 16 + lr;
            #pragma unroll
            for (int ks = 0; ks < 2; ++ks) {
                const int koff = (ks * 32 + lg * 8) ^ swf;
                const bf16x8 bh = *(const bf16x8*)&Kh_s[key][koff];
                const bf16x8 bl = *(const bf16x8*)&Kl_s[key][koff];
                s[kb] = __builtin_amdgcn_mfma_f32_16x16x32_bf16(qh_[ks], bh, s[kb], 0, 0, 0);
                s[kb] = __builtin_amdgcn_mfma_f32_16x16x32_bf16(qh_[ks], bl, s[kb], 0, 0, 0);
                s[kb] = __builtin_amdgcn_mfma_f32_16x16x32_bf16(ql_[ks], bh, s[kb], 0, 0, 0);
            }
        }
        __builtin_amdgcn_s_setprio(0);

        if (kbase + 64 > N_TOK) {
            #pragma unroll
            for (int kb = 0; kb < 4; ++kb)
                if (kbase + kb * 16 + lr >= N_TOK) {
                    #pragma unroll
                    for (int r = 0; r < 4; ++r) s[kb][r] = -1e30f;
                }
        }

        // ---- online softmax ----
        float mt[4], al[4];
        #pragma unroll
        for (int r = 0; r < 4; ++r)
            mt[r] = fmaxf(fmaxf(s[0][r], s[1][r]), fmaxf(s[2][r], s[3][r]));
        #pragma unroll
        for (int r = 0; r < 4; ++r) {
            mt[r] = fmaxf(mt[r], __shfl_xor(mt[r], 1));
            mt[r] = fmaxf(mt[r], __shfl_xor(mt[r], 2));
            mt[r] = fmaxf(mt[r], __shfl_xor(mt[r], 4));
            mt[r] = fmaxf(mt[r], __shfl_xor(mt[r], 8));
        }
        #pragma unroll
        for (int r = 0; r < 4; ++r) {
            const float mn = fmaxf(m0[r], mt[r]);
            al[r] = __expf(m0[r] - mn);
            m0[r] = mn;
        }
        #pragma unroll
        for (int kb = 0; kb < 4; ++kb)
            #pragma unroll
            for (int r = 0; r < 4; ++r)
                s[kb][r] = __expf(s[kb][r] - m0[r]);
        #pragma unroll
        for (int r = 0; r < 4; ++r)
            l0[r] = l0[r] * al[r] + (s[0][r] + s[1][r] + s[2][r] + s[3][r]);
        #pragma unroll
        for (int db = 0; db < 4; ++db)
            #pragma unroll
            for (int r = 0; r < 4; ++r) acc[db][r] *= al[r];

        // ---- pack P fp16 -> wave-private LDS rows ----
        #pragma unroll
        for (int r = 0; r < 4; ++r) {
            const int rw = w * 16 + lg * 4 + r;
            const int swp = (rw & 7) << 3;
            #pragma unroll
            for (int kb = 0; kb < 4; ++kb)
                P2[rw][(kb * 16 + lr) ^ swp] = __half_as_ushort(__float2half(s[kb][r]));
        }

        // ---- PV (fp16: P x Vhi + P x Vlo) ----
        const int arow = w * 16 + lr;
        const int swpa = (arow & 7) << 3;
        #pragma unroll
        for (int ks = 0; ks < 2; ++ks) {
            const int kb8 = ks * 32 + lg * 8;
            const f16x8 pa = as_f16x8(*(const u16x8*)&P2[arow][kb8 ^ swpa]);
            __builtin_amdgcn_s_setprio(1);
            #pragma unroll
            for (int db = 0; db < 4; ++db) {
                const int vr = db * 16 + lr;
                const int koff = kb8 ^ swf;
                const f16x8 vh = as_f16x8(*(const u16x8*)&Vh_s[vr][koff]);
                const f16x8 vl = as_f16x8(*(const u16x8*)&Vl_s[vr][koff]);
                acc[db] = __builtin_amdgcn_mfma_f32_16x16x32_f16(pa, vh, acc[db], 0, 0, 0);
                acc[db] = __builtin_amdgcn_mfma_f32_16x16x32_f16(pa, vl, acc[db], 0, 0, 0);
            }
            __builtin_amdgcn_s_setprio(0);
        }
    }

    // ---- epilogue ----
    #pragma unroll
    for (int r = 0; r < 4; ++r) {
        l0[r] += __shfl_xor(l0[r], 1);
        l0[r] += __shfl_xor(l0[r], 2);
        l0[r] += __shfl_xor(l0[r], 4);
        l0[r] += __shfl_xor(l0[r], 8);
    }
    const size_t pb = (((size_t)sh * NH + head) * NQT + qb) << 6;
    float* pout = Pacc + (pb << 6);
    #pragma unroll
    for (int r = 0; r < 4; ++r) {
        const int lrow = w * 16 + lg * 4 + r;
        #pragma unroll
        for (int db = 0; db < 4; ++db)
            pout[(size_t)lrow * 64 + db * 16 + lr] = acc[db][r];
        if (lr == 0)
            PmL[pb + lrow] = make_float2(m0[r], l0[r]);
    }
}

// ---------------- Kernel 2b: combine shards ----------------
__global__ __launch_bounds__(256)
void attn_combine(const float* __restrict__ Pacc, const float2* __restrict__ PmL,
                  u16* __restrict__ Ohi, u16* __restrict__ Olo, int SPLITS)
{
    const int qb = blockIdx.x, h = blockIdx.y;
    const int tid = threadIdx.x;
    const int er = tid >> 2, eu = tid & 3;
    const int row = qb * 64 + er;
    if (row >= N_TOK) return;

    float ms[4], ls[4];
    float m = -1e30f;
    for (int s = 0; s < SPLITS; ++s) {
        const float2 p = PmL[((((size_t)s * NH + h) * NQT + qb) << 6) + er];
        ms[s] = p.x; ls[s] = p.y;
        m = fmaxf(m, p.x);
    }
    float L = 0.f, Ws[4];
    for (int s = 0; s < SPLITS; ++s) { Ws[s] = __expf(ms[s] - m); L += ls[s] * Ws[s]; }
    const float inv = 1.f / L;

    float o[16];
    #pragma unroll
    for (int j = 0; j < 16; ++j) o[j] = 0.f;
    for (int s = 0; s < SPLITS; ++s) {
        const float* src = Pacc + ((((((size_t)s * NH + h) * NQT + qb) << 6) + er) << 6) + (eu << 4);
        const float wgt = Ws[s];
        #pragma unroll
        for (int c = 0; c < 4; ++c) {
            const float4 f = *(const float4*)(src + c * 4);
            o[c * 4 + 0] += wgt * f.x;
            o[c * 4 + 1] += wgt * f.y;
            o[c * 4 + 2] += wgt * f.z;
            o[c * 4 + 3] += wgt * f.w;
        }
    }
    u16x8 h0, h1, l0v, l1v;
    #pragma unroll
    for (int j = 0; j < 8; ++j) { u16 hh, ll; split1(o[j] * inv, hh, ll); h0[j] = hh; l0v[j] = ll; }
    #pragma unroll
    for (int j = 0; j < 8; ++j) { u16 hh, ll; split1(o[8 + j] * inv, hh, ll); h1[j] = hh; l1v[j] = ll; }
    u16* dh = Ohi + (size_t)row * CDIM + h * HD + (eu << 4);
    u16* dl = Olo + (size_t)row * CDIM + h * HD + (eu << 4);
    *(u16x8*)dh = h0;  *(u16x8*)(dh + 8) = h1;
    *(u16x8*)dl = l0v; *(u16x8*)(dl + 8) = l1v;
}

// ---------------- Kernel 3: output projection via MFMA hi/lo ----------------
__global__ __launch_bounds__(256)
void proj_mfma(const u16* __restrict__ Ahi, const u16* __restrict__ Alo,
               const u16* __restrict__ Whi, const u16* __restrict__ Wlo,
               const float* __restrict__ bp, float* __restrict__ out)
{
    __shared__ __align__(16) u16 Ah[64][64], Al[64][64], Bh[64][64], Bl[64][64];

    const int rb = blockIdx.x;
    const int colbase = blockIdx.y * 64;
    const int tid = threadIdx.x;
    const int w = tid >> 6, l = tid & 63;
    const int lr = l & 15, lg = l >> 4;

    const int srow = tid >> 2, sch = (tid & 3) << 4;
    int arow = rb * 64 + srow;
    if (arow >= N_TOK) arow = N_TOK - 1;
    const size_t abase = (size_t)arow * CDIM + sch;
    const size_t bbase = (size_t)(colbase + srow) * CDIM + sch;

    f32x4 acc[4];
    #pragma unroll
    for (int i = 0; i < 4; ++i) acc[i] = (f32x4){0.f, 0.f, 0.f, 0.f};

    const int sw = (srow & 7) << 3;
    const int swf = (lr & 7) << 3;

    for (int k0 = 0; k0 < CDIM; k0 += 64) {
        const u16x8 a0h = *(const u16x8*)(Ahi + abase + k0);
        const u16x8 a1h = *(const u16x8*)(Ahi + abase + k0 + 8);
        const u16x8 a0l = *(const u16x8*)(Alo + abase + k0);
        const u16x8 a1l = *(const u16x8*)(Alo + abase + k0 + 8);
        const u16x8 b0h = *(const u16x8*)(Whi + bbase + k0);
        const u16x8 b1h = *(const u16x8*)(Whi + bbase + k0 + 8);
        const u16x8 b0l = *(const u16x8*)(Wlo + bbase + k0);
        const u16x8 b1l = *(const u16x8*)(Wlo + bbase + k0 + 8);
        __syncthreads();
        *(u16x8*)&Ah[srow][(sch + 0) ^ sw] = a0h;
        *(u16x8*)&Ah[srow][(sch + 8) ^ sw] = a1h;
        *(u16x8*)&Al[srow][(sch + 0) ^ sw] = a0l;
        *(u16x8*)&Al[srow][(sch + 8) ^ sw] = a1l;
        *(u16x8*)&Bh[srow][(sch + 0) ^ sw] = b0h;
        *(u16x8*)&Bh[srow][(sch + 8) ^ sw] = b1h;
        *(u16x8*)&Bl[srow][(sch + 0) ^ sw] = b0l;
        *(u16x8*)&Bl[srow][(sch + 8) ^ sw] = b1l;
        __syncthreads();
        #pragma unroll
        for (int ks = 0; ks < 2; ++ks) {
            const int koff = (ks * 32 + lg * 8) ^ swf;
            const bf16x8 ah_ = *(const bf16x8*)&Ah[w * 16 + lr][koff];
            const bf16x8 al_ = *(const bf16x8*)&Al[w * 16 + lr][koff];
            #pragma unroll
            for (int cbk = 0; cbk < 4; ++cbk) {
                const bf16x8 bh_ = *(const bf16x8*)&Bh[cbk * 16 + lr][koff];
                const bf16x8 bl_ = *(const bf16x8*)&Bl[cbk * 16 + lr][koff];
                acc[cbk] = __builtin_amdgcn_mfma_f32_16x16x32_bf16(ah_, bh_, acc[cbk], 0, 0, 0);
                acc[cbk] = __builtin_amdgcn_mfma_f32_16x16x32_bf16(ah_, bl_, acc[cbk], 0, 0, 0);
                acc[cbk] = __builtin_amdgcn_mfma_f32_16x16x32_bf16(al_, bh_, acc[cbk], 0, 0, 0);
            }
        }
    }

    #pragma unroll
    for (int cbk = 0; cbk < 4; ++cbk) {
        const float bb = bp[colbase + cbk * 16 + lr];
        #pragma unroll
        for (int r = 0; r < 4; ++r) {
            const int row = rb * 64 + w * 16 + lg * 4 + r;
            if (row < N_TOK)
                out[(size_t)row * CDIM + colbase + cbk * 16 + lr] = acc[cbk][r] + bb;
        }
    }
}

extern "C" void kernel_launch(void* const* d_in, const int* in_sizes, int n_in,
                              void* d_out, int out_size, void* d_ws, size_t ws_size,
                              hipStream_t stream)
{
    const float* q_tokens = (const float*)d_in[0];
    const float* t_tokens = (const float*)d_in[1];
    const float* pos2d    = (const float*)d_in[2];
    const float* tposes   = (const float*)d_in[3];
    const float* Wqkv     = (const float*)d_in[4];
    const float* bqkv     = (const float*)d_in[5];
    const float* Wproj    = (const float*)d_in[6];
    const float* bproj    = (const float*)d_in[7];
    float* out = (float*)d_out;

    const size_t PQ = (size_t)NH * N_TOK * HD;
    const size_t PV_ = (size_t)NH * HD * NVP;
    const size_t PX = (size_t)N_TOK * CDIM;
    const size_t PW = (size_t)QKV_COLS * CDIM;

    u16* base = (u16*)d_ws;
    u16* Qhi  = base;
    u16* Qlo  = Qhi + PQ;
    u16* Khi  = Qlo + PQ;
    u16* Klo  = Khi + PQ;
    u16* Vthi = Klo + PQ;
    u16* Vtlo = Vthi + PV_;
    u16* XOhi = Vtlo + PV_;
    u16* XOlo = XOhi + PX;
    u16* WThi = XOlo + PX;
    u16* WTlo = WThi + PW;
    u16* planes_end = WTlo + PW;

    const size_t planes_bytes = (size_t)(planes_end - base) * sizeof(u16);
    const size_t accElems = (size_t)NH * NQT * 64 * 64;
    const size_t mlElems  = (size_t)NH * NQT * 64;
    const size_t per_shard = accElems * 4 + mlElems * 8;

    int SPLITS = 1;
    for (int cand = 4; cand >= 2; --cand) {
        if (planes_bytes + (size_t)cand * per_shard <= ws_size) { SPLITS = cand; break; }
    }
    float* Pacc = (float*)((char*)d_ws + planes_bytes);
    float2* PmL = (float2*)(Pacc + (size_t)SPLITS * accElems);
    const int TS = (NQT + SPLITS - 1) / SPLITS;

    conv_x<<<dim3((N_TOK * CDIM / 4 + 255) / 256), 256, 0, stream>>>(q_tokens, t_tokens, XOhi, XOlo);
    conv_wT<<<dim3(CDIM / 64, QKV_COLS / 64), 256, 0, stream>>>(Wqkv, QKV_COLS, WThi, WTlo);
    hipMemsetAsync(Vthi, 0, 2 * PV_ * sizeof(u16), stream);

    dim3 g1((N_TOK + 127) / 128, 36);
    qkv_mfma<<<g1, 256, 0, stream>>>(XOhi, XOlo, WThi, WTlo, bqkv, pos2d, tposes,
                                     Qhi, Qlo, Khi, Klo, Vthi, Vtlo);

    conv_wT<<<dim3(CDIM / 64, CDIM / 64), 256, 0, stream>>>(Wproj, CDIM, WThi, WTlo);

    dim3 g2(NQT, NH, SPLITS);
    attn_shard<<<g2, 256, 0, stream>>>(Qhi, Qlo, Khi, Klo, Vthi, Vtlo, Pacc, PmL, TS, SPLITS);

    dim3 g2b(NQT, NH);
    attn_combine<<<g2b, 256, 0, stream>>>(Pacc, PmL, XOhi, XOlo, SPLITS);

    dim3 g3((N_TOK + 63) / 64, CDIM / 64);
    proj_mfma<<<g3, 256, 0, stream>>>(XOhi, XOlo, WThi, WTlo, bproj, out);
}

// Round 10
// 206.117 us; speedup vs baseline: 1.3383x; 1.0587x over previous
//
#include <hip/hip_runtime.h>
#include <hip/hip_bf16.h>
#include <hip/hip_fp16.h>
#include <math.h>

#define N_TOK 2884
#define HW_IMG 576
#define NT_TOK 577
#define CDIM 768
#define NH 12
#define HD 64
#define QKV_COLS 2304
#define NVP 2944   // padded token stride for V^T plane
#define NQT 46     // number of 64-row q tiles (attention)

typedef float f32x4 __attribute__((ext_vector_type(4)));
typedef short bf16x8 __attribute__((ext_vector_type(8)));
typedef _Float16 f16x8 __attribute__((ext_vector_type(8)));
typedef unsigned short u16;
typedef unsigned short u16x8 __attribute__((ext_vector_type(8)));
typedef unsigned short u16x4 __attribute__((ext_vector_type(4)));

static __device__ __forceinline__ u16 f2bf(float f) {
    union { __hip_bfloat16 b; u16 u; } cv;
    cv.b = __float2bfloat16(f);
    return cv.u;
}
static __device__ __forceinline__ float bf2f(u16 h) {
    return __uint_as_float(((unsigned)h) << 16);
}
static __device__ __forceinline__ void split1(float f, u16& h, u16& l) {
    h = f2bf(f);
    l = f2bf(f - bf2f(h));
}
static __device__ __forceinline__ f16x8 as_f16x8(u16x8 u) {
    union { u16x8 u; f16x8 h; } c; c.u = u; return c.h;
}

// ---------------- conv_x ----------------
__global__ __launch_bounds__(256)
void conv_x(const float* __restrict__ q, const float* __restrict__ t,
            u16* __restrict__ Xhi, u16* __restrict__ Xlo)
{
    const int i = (blockIdx.x * 256 + threadIdx.x) * 4;
    const int SPLIT = HW_IMG * CDIM;
    const float4 v = (i < SPLIT) ? *(const float4*)(q + i) : *(const float4*)(t + (i - SPLIT));
    u16x4 h, l;
    u16 hh, ll;
    split1(v.x, hh, ll); h[0] = hh; l[0] = ll;
    split1(v.y, hh, ll); h[1] = hh; l[1] = ll;
    split1(v.z, hh, ll); h[2] = hh; l[2] = ll;
    split1(v.w, hh, ll); h[3] = hh; l[3] = ll;
    *(u16x4*)(Xhi + i) = h;
    *(u16x4*)(Xlo + i) = l;
}

// ---------------- conv_wT ----------------
__global__ __launch_bounds__(256)
void conv_wT(const float* __restrict__ W, int ncols,
             u16* __restrict__ Thi, u16* __restrict__ Tlo)
{
    __shared__ float T[64][65];
    const int k0 = blockIdx.x * 64;
    const int n0 = blockIdx.y * 64;
    const int tid = threadIdx.x;
    {
        const int kr = tid >> 2, nch = (tid & 3) << 4;
        const float* src = W + (size_t)(k0 + kr) * ncols + n0 + nch;
        #pragma unroll
        for (int c = 0; c < 4; ++c) {
            const float4 f = *(const float4*)(src + c * 4);
            T[kr][nch + c * 4 + 0] = f.x;
            T[kr][nch + c * 4 + 1] = f.y;
            T[kr][nch + c * 4 + 2] = f.z;
            T[kr][nch + c * 4 + 3] = f.w;
        }
    }
    __syncthreads();
    const int nr = tid >> 2, kch = (tid & 3) << 4;
    u16x8 h0, h1, l0v, l1v;
    #pragma unroll
    for (int j = 0; j < 8; ++j) { u16 hh, ll; split1(T[kch + j][nr], hh, ll); h0[j] = hh; l0v[j] = ll; }
    #pragma unroll
    for (int j = 0; j < 8; ++j) { u16 hh, ll; split1(T[kch + 8 + j][nr], hh, ll); h1[j] = hh; l1v[j] = ll; }
    const size_t dst = (size_t)(n0 + nr) * CDIM + k0 + kch;
    *(u16x8*)(Thi + dst) = h0;     *(u16x8*)(Thi + dst + 8) = h1;
    *(u16x8*)(Tlo + dst) = l0v;    *(u16x8*)(Tlo + dst + 8) = l1v;
}

// ---------------- Kernel 1: QKV via MFMA hi/lo, 128x64 tile ----------------
// Q/K planes bf16 hi/lo; V^T plane single fp16 (PV error analysis: ~1e-5 contribution).
__global__ __launch_bounds__(256, 3)
void qkv_mfma(const u16* __restrict__ Xhi, const u16* __restrict__ Xlo,
              const u16* __restrict__ Whi, const u16* __restrict__ Wlo,
              const float* __restrict__ bqkv,
              const float* __restrict__ pos2d, const float* __restrict__ tposes,
              u16* __restrict__ Qhi, u16* __restrict__ Qlo,
              u16* __restrict__ Khi, u16* __restrict__ Klo,
              u16* __restrict__ Vthi)
{
    __shared__ __align__(16) char smem[49152];
    u16 (*Ah)[64] = (u16(*)[64])(smem);
    u16 (*Al)[64] = (u16(*)[64])(smem + 16384);
    u16 (*Bh)[64] = (u16(*)[64])(smem + 32768);
    u16 (*Bl)[64] = (u16(*)[64])(smem + 40960);
    float (*Ct)[65] = (float(*)[65])(smem);

    const int rb = blockIdx.x;
    const int cb = blockIdx.y;
    const int which = cb / NH;
    const int h = cb - which * NH;
    const int colbase = cb * 64;
    const int tid = threadIdx.x;
    const int w = tid >> 6, l = tid & 63;
    const int lr = l & 15, lg = l >> 4;

    const int sa_r = tid >> 1;
    const int sa_c = (tid & 1) << 5;
    int arow = rb * 128 + sa_r;
    if (arow >= N_TOK) arow = N_TOK - 1;
    const size_t abase = (size_t)arow * CDIM + sa_c;
    const int swa_ = (sa_r & 7) << 3;
    const int sb_r = tid >> 2;
    const int sb_c = (tid & 3) << 4;
    const size_t bbase = (size_t)(colbase + sb_r) * CDIM + sb_c;
    const int swb_ = (sb_r & 7) << 3;

    const int swf = (lr & 7) << 3;

    f32x4 acc[2][4];
    #pragma unroll
    for (int rf = 0; rf < 2; ++rf)
        #pragma unroll
        for (int i = 0; i < 4; ++i) acc[rf][i] = (f32x4){0.f, 0.f, 0.f, 0.f};

    for (int k0 = 0; k0 < CDIM; k0 += 64) {
        u16x8 a_h[4], a_l[4], b_h[2], b_l[2];
        #pragma unroll
        for (int c = 0; c < 4; ++c) {
            a_h[c] = *(const u16x8*)(Xhi + abase + k0 + c * 8);
            a_l[c] = *(const u16x8*)(Xlo + abase + k0 + c * 8);
        }
        #pragma unroll
        for (int c = 0; c < 2; ++c) {
            b_h[c] = *(const u16x8*)(Whi + bbase + k0 + c * 8);
            b_l[c] = *(const u16x8*)(Wlo + bbase + k0 + c * 8);
        }
        __syncthreads();
        #pragma unroll
        for (int c = 0; c < 4; ++c) {
            *(u16x8*)&Ah[sa_r][(sa_c + c * 8) ^ swa_] = a_h[c];
            *(u16x8*)&Al[sa_r][(sa_c + c * 8) ^ swa_] = a_l[c];
        }
        #pragma unroll
        for (int c = 0; c < 2; ++c) {
            *(u16x8*)&Bh[sb_r][(sb_c + c * 8) ^ swb_] = b_h[c];
            *(u16x8*)&Bl[sb_r][(sb_c + c * 8) ^ swb_] = b_l[c];
        }
        __syncthreads();
        #pragma unroll
        for (int ks = 0; ks < 2; ++ks) {
            const int koff = (ks * 32 + lg * 8) ^ swf;
            const bf16x8 ah0 = *(const bf16x8*)&Ah[w * 32 + lr][koff];
            const bf16x8 al0 = *(const bf16x8*)&Al[w * 32 + lr][koff];
            const bf16x8 ah1 = *(const bf16x8*)&Ah[w * 32 + 16 + lr][koff];
            const bf16x8 al1 = *(const bf16x8*)&Al[w * 32 + 16 + lr][koff];
            #pragma unroll
            for (int cbk = 0; cbk < 4; ++cbk) {
                const bf16x8 bh_ = *(const bf16x8*)&Bh[cbk * 16 + lr][koff];
                const bf16x8 bl_ = *(const bf16x8*)&Bl[cbk * 16 + lr][koff];
                acc[0][cbk] = __builtin_amdgcn_mfma_f32_16x16x32_bf16(ah0, bh_, acc[0][cbk], 0, 0, 0);
                acc[0][cbk] = __builtin_amdgcn_mfma_f32_16x16x32_bf16(ah0, bl_, acc[0][cbk], 0, 0, 0);
                acc[0][cbk] = __builtin_amdgcn_mfma_f32_16x16x32_bf16(al0, bh_, acc[0][cbk], 0, 0, 0);
                acc[1][cbk] = __builtin_amdgcn_mfma_f32_16x16x32_bf16(ah1, bh_, acc[1][cbk], 0, 0, 0);
                acc[1][cbk] = __builtin_amdgcn_mfma_f32_16x16x32_bf16(ah1, bl_, acc[1][cbk], 0, 0, 0);
                acc[1][cbk] = __builtin_amdgcn_mfma_f32_16x16x32_bf16(al1, bh_, acc[1][cbk], 0, 0, 0);
            }
        }
    }

    __syncthreads();
    #pragma unroll
    for (int rf = 0; rf < 2; ++rf)
        #pragma unroll
        for (int cbk = 0; cbk < 4; ++cbk)
            #pragma unroll
            for (int r = 0; r < 4; ++r)
                Ct[w * 32 + rf * 16 + lg * 4 + r][cbk * 16 + lr] =
                    acc[rf][cbk][r] + bqkv[colbase + cbk * 16 + lr];
    __syncthreads();

    if (which < 2) {
        #pragma unroll
        for (int it = 0; it < 2; ++it) {
            const int item = it * 256 + tid;
            const int er = item >> 2;
            const int eu = item & 3;
            const int n = rb * 128 + er;
            if (n < N_TOK) {
                float outv[16];
                const bool is_img = (n < HW_IMG);
                int ts = 0, tj = 0;
                if (!is_img) { const int m = n - HW_IMG; ts = m / NT_TOK; tj = m - ts * NT_TOK; }

                if (is_img) {
                    const float p = (eu < 2) ? pos2d[2 * n] : pos2d[2 * n + 1];
                    const bool lowhalf = ((eu & 1) == 0);
                    #pragma unroll
                    for (int dd = 0; dd < 16; ++dd) {
                        const int d = (eu << 4) + dd;
                        float sv, cv;
                        sincosf(p * expf((float)dd * -0.28782313662425574f), &sv, &cv);
                        const float rot = lowhalf ? -Ct[er][d + 16] : Ct[er][d - 16];
                        outv[dd] = Ct[er][d] * cv + rot * sv;
                    }
                } else if (tj < HW_IMG) {
                    #pragma unroll
                    for (int dd = 0; dd < 16; ++dd) {
                        const int d = (eu << 4) + dd;
                        float val = Ct[er][d];
                        if (d < 30) {
                            const int g = d / 3;
                            const float* R = tposes + ts * 16 + (d - g * 3) * 4;
                            val = R[0] * Ct[er][g * 3] + R[1] * Ct[er][g * 3 + 1] + R[2] * Ct[er][g * 3 + 2];
                        }
                        outv[dd] = val;
                    }
                } else {
                    #pragma unroll
                    for (int dd = 0; dd < 16; ++dd) outv[dd] = Ct[er][(eu << 4) + dd];
                }

                const float scale = (which == 0) ? 0.125f : 1.0f;
                u16x8 h0, h1, l0v, l1v;
                #pragma unroll
                for (int j = 0; j < 8; ++j) { u16 hh, ll; split1(outv[j] * scale, hh, ll); h0[j] = hh; l0v[j] = ll; }
                #pragma unroll
                for (int j = 0; j < 8; ++j) { u16 hh, ll; split1(outv[8 + j] * scale, hh, ll); h1[j] = hh; l1v[j] = ll; }
                u16* dh = (which == 0 ? Qhi : Khi) + ((size_t)h * N_TOK + n) * HD + (eu << 4);
                u16* dl = (which == 0 ? Qlo : Klo) + ((size_t)h * N_TOK + n) * HD + (eu << 4);
                *(u16x8*)dh = h0;  *(u16x8*)(dh + 8) = h1;
                *(u16x8*)dl = l0v; *(u16x8*)(dl + 8) = l1v;
            }
        }
    } else {
        // V: single fp16, transposed plane [h][d][token]; pad tokens stay zero
        #pragma unroll
        for (int it = 0; it < 2; ++it) {
            const int item = it * 256 + tid;
            const int vd_ = item >> 3;
            const int vch = (item & 7) << 4;
            const int tokbase = rb * 128 + vch;
            u16 th[16];
            #pragma unroll
            for (int j = 0; j < 16; ++j)
                th[j] = __half_as_ushort(__float2half(Ct[vch + j][vd_]));
            u16* dh = Vthi + (size_t)(h * HD + vd_) * NVP + tokbase;
            if (tokbase + 16 <= N_TOK) {
                *(u16x8*)dh = *(u16x8*)&th[0];  *(u16x8*)(dh + 8) = *(u16x8*)&th[8];
            } else {
                #pragma unroll
                for (int j = 0; j < 16; ++j)
                    if (tokbase + j < N_TOK) dh[j] = th[j];
            }
        }
    }
}

// ---------------- Kernel 2: split-K flash attention; QK bf16 hi/lo, PV single fp16 ----------------
// 64 q-rows/block, reg-prefetch one tile ahead, 2 barriers/tile, wave-private P,
// exact defer-max skip. LDS 32 KB.
__global__ __launch_bounds__(256, 3)
void attn_shard(const u16* __restrict__ Qhi, const u16* __restrict__ Qlo,
                const u16* __restrict__ Khi, const u16* __restrict__ Klo,
                const u16* __restrict__ Vthi,
                float* __restrict__ Pacc, float2* __restrict__ PmL,
                int TS, int SPLITS)
{
    __shared__ __align__(16) u16 Kh_s[64][64], Kl_s[64][64];   // bf16 hi/lo
    __shared__ __align__(16) u16 Vh_s[64][64];                 // fp16 single
    __shared__ __align__(16) u16 P2[64][64];                   // fp16 P (wave-private rows)

    int qb, head, sh;
    {
        const int flat = blockIdx.x + NQT * (blockIdx.y + NH * blockIdx.z);
        if (SPLITS == 4) {
            const int grp = flat & 7;
            const int rest = flat >> 3;
            qb = rest % NQT;
            const int hs = grp + 8 * (rest / NQT);
            head = hs % NH;
            sh = hs / NH;
        } else {
            qb = blockIdx.x; head = blockIdx.y; sh = blockIdx.z;
        }
    }
    const int tid = threadIdx.x;
    const int w = tid >> 6, l = tid & 63;
    const int lr = l & 15, lg = l >> 4;

    const int kt_begin = sh * TS;
    const int kt_end = min(NQT, kt_begin + TS);

    bf16x8 qh_[2], ql_[2];
    {
        int row = qb * 64 + w * 16 + lr;
        if (row >= N_TOK) row = N_TOK - 1;
        const u16* qph = Qhi + ((size_t)head * N_TOK + row) * HD;
        const u16* qpl = Qlo + ((size_t)head * N_TOK + row) * HD;
        #pragma unroll
        for (int ks = 0; ks < 2; ++ks) {
            qh_[ks] = *(const bf16x8*)(qph + ks * 32 + lg * 8);
            ql_[ks] = *(const bf16x8*)(qpl + ks * 32 + lg * 8);
        }
    }

    float m0[4] = {-1e30f, -1e30f, -1e30f, -1e30f};
    float l0[4] = {0.f, 0.f, 0.f, 0.f};
    f32x4 acc[4];
    #pragma unroll
    for (int db = 0; db < 4; ++db) acc[db] = (f32x4){0.f, 0.f, 0.f, 0.f};

    const int skey = tid >> 2, sch = (tid & 3) << 4;
    const int vd_ = tid >> 2, vch = (tid & 3) << 4;
    const int swk = (skey & 7) << 3;
    const int swv = (vd_ & 7) << 3;
    const int swf = (lr & 7) << 3;
    const u16* KhH = Khi + (size_t)head * N_TOK * HD;
    const u16* KlH = Klo + (size_t)head * N_TOK * HD;
    const size_t vrowbase = (size_t)(head * HD + vd_) * NVP;

    u16x8 rk0h, rk1h, rk0l, rk1l, rv0h, rv1h;
    auto LOADT = [&](int kt) {
        const int kbase = kt << 6;
        int krow = kbase + skey;
        if (krow >= N_TOK) krow = N_TOK - 1;
        const u16* kph = KhH + (size_t)krow * HD + sch;
        const u16* kpl = KlH + (size_t)krow * HD + sch;
        rk0h = *(const u16x8*)kph;  rk1h = *(const u16x8*)(kph + 8);
        rk0l = *(const u16x8*)kpl;  rk1l = *(const u16x8*)(kpl + 8);
        const u16* vph = Vthi + vrowbase + kbase + vch;
        rv0h = *(const u16x8*)vph;  rv1h = *(const u16x8*)(vph + 8);
    };
    LOADT(kt_begin);

    for (int kt = kt_begin; kt < kt_end; ++kt) {
        const int kbase = kt << 6;

        __syncthreads();
        *(u16x8*)&Kh_s[skey][(sch + 0) ^ swk] = rk0h;
        *(u16x8*)&Kh_s[skey][(sch + 8) ^ swk] = rk1h;
        *(u16x8*)&Kl_s[skey][(sch + 0) ^ swk] = rk0l;
        *(u16x8*)&Kl_s[skey][(sch + 8) ^ swk] = rk1l;
        *(u16x8*)&Vh_s[vd_][(vch + 0) ^ swv] = rv0h;
        *(u16x8*)&Vh_s[vd_][(vch + 8) ^ swv] = rv1h;
        if (kt + 1 < kt_end) LOADT(kt + 1);
        __syncthreads();

        // ---- S = Q K^T (bf16 hi/lo 3-product) ----
        f32x4 s[4];
        __builtin_amdgcn_s_setprio(1);
        #pragma unroll
        for (int kb = 0; kb < 4; ++kb) {
            s[kb] = (f32x4){0.f, 0.f, 0.f, 0.f};
            const int key = kb * 16 + lr;
            #pragma unroll
            for (int ks = 0; ks < 2; ++ks) {
                const int koff = (ks * 32 + lg * 8) ^ swf;
                const bf16x8 bh = *(const bf16x8*)&Kh_s[key][koff];
                const bf16x8 bl = *(const bf16x8*)&Kl_s[key][koff];
                s[kb] = __builtin_amdgcn_mfma_f32_16x16x32_bf16(qh_[ks], bh, s[kb], 0, 0, 0);
                s[kb] = __builtin_amdgcn_mfma_f32_16x16x32_bf16(qh_[ks], bl, s[kb], 0, 0, 0);
                s[kb] = __builtin_amdgcn_mfma_f32_16x16x32_bf16(ql_[ks], bh, s[kb], 0, 0, 0);
            }
        }
        __builtin_amdgcn_s_setprio(0);

        if (kbase + 64 > N_TOK) {
            #pragma unroll
            for (int kb = 0; kb < 4; ++kb)
                if (kbase + kb * 16 + lr >= N_TOK) {
                    #pragma unroll
                    for (int r = 0; r < 4; ++r) s[kb][r] = -1e30f;
                }
        }

        // ---- online softmax with exact defer-max skip ----
        float mt[4];
        #pragma unroll
        for (int r = 0; r < 4; ++r)
            mt[r] = fmaxf(fmaxf(s[0][r], s[1][r]), fmaxf(s[2][r], s[3][r]));
        #pragma unroll
        for (int r = 0; r < 4; ++r) {
            mt[r] = fmaxf(mt[r], __shfl_xor(mt[r], 1));
            mt[r] = fmaxf(mt[r], __shfl_xor(mt[r], 2));
            mt[r] = fmaxf(mt[r], __shfl_xor(mt[r], 4));
            mt[r] = fmaxf(mt[r], __shfl_xor(mt[r], 8));
        }
        const bool newmax = __any((mt[0] > m0[0]) | (mt[1] > m0[1]) |
                                  (mt[2] > m0[2]) | (mt[3] > m0[3]));
        if (newmax) {
            // rescale path (al==1 exactly when mt<=m0, so skip is bit-exact)
            float al[4];
            #pragma unroll
            for (int r = 0; r < 4; ++r) {
                const float mn = fmaxf(m0[r], mt[r]);
                al[r] = __expf(m0[r] - mn);
                m0[r] = mn;
            }
            #pragma unroll
            for (int r = 0; r < 4; ++r) l0[r] *= al[r];
            #pragma unroll
            for (int db = 0; db < 4; ++db)
                #pragma unroll
                for (int r = 0; r < 4; ++r) acc[db][r] *= al[r];
        }
        #pragma unroll
        for (int kb = 0; kb < 4; ++kb)
            #pragma unroll
            for (int r = 0; r < 4; ++r)
                s[kb][r] = __expf(s[kb][r] - m0[r]);
        #pragma unroll
        for (int r = 0; r < 4; ++r)
            l0[r] += s[0][r] + s[1][r] + s[2][r] + s[3][r];

        // ---- pack P fp16 -> wave-private LDS rows ----
        #pragma unroll
        for (int r = 0; r < 4; ++r) {
            const int rw = w * 16 + lg * 4 + r;
            const int swp = (rw & 7) << 3;
            #pragma unroll
            for (int kb = 0; kb < 4; ++kb)
                P2[rw][(kb * 16 + lr) ^ swp] = __half_as_ushort(__float2half(s[kb][r]));
        }

        // ---- PV (single fp16) ----
        const int arow = w * 16 + lr;
        const int swpa = (arow & 7) << 3;
        #pragma unroll
        for (int ks = 0; ks < 2; ++ks) {
            const int kb8 = ks * 32 + lg * 8;
            const f16x8 pa = as_f16x8(*(const u16x8*)&P2[arow][kb8 ^ swpa]);
            __builtin_amdgcn_s_setprio(1);
            #pragma unroll
            for (int db = 0; db < 4; ++db) {
                const int vr = db * 16 + lr;
                const f16x8 vh = as_f16x8(*(const u16x8*)&Vh_s[vr][kb8 ^ swf]);
                acc[db] = __builtin_amdgcn_mfma_f32_16x16x32_f16(pa, vh, acc[db], 0, 0, 0);
            }
            __builtin_amdgcn_s_setprio(0);
        }
    }

    // ---- epilogue ----
    #pragma unroll
    for (int r = 0; r < 4; ++r) {
        l0[r] += __shfl_xor(l0[r], 1);
        l0[r] += __shfl_xor(l0[r], 2);
        l0[r] += __shfl_xor(l0[r], 4);
        l0[r] += __shfl_xor(l0[r], 8);
    }
    const size_t pb = (((size_t)sh * NH + head) * NQT + qb) << 6;
    float* pout = Pacc + (pb << 6);
    #pragma unroll
    for (int r = 0; r < 4; ++r) {
        const int lrow = w * 16 + lg * 4 + r;
        #pragma unroll
        for (int db = 0; db < 4; ++db)
            pout[(size_t)lrow * 64 + db * 16 + lr] = acc[db][r];
        if (lr == 0)
            PmL[pb + lrow] = make_float2(m0[r], l0[r]);
    }
}

// ---------------- Kernel 2b: combine shards ----------------
__global__ __launch_bounds__(256)
void attn_combine(const float* __restrict__ Pacc, const float2* __restrict__ PmL,
                  u16* __restrict__ Ohi, u16* __restrict__ Olo, int SPLITS)
{
    const int qb = blockIdx.x, h = blockIdx.y;
    const int tid = threadIdx.x;
    const int er = tid >> 2, eu = tid & 3;
    const int row = qb * 64 + er;
    if (row >= N_TOK) return;

    float ms[4], ls[4];
    float m = -1e30f;
    for (int s = 0; s < SPLITS; ++s) {
        const float2 p = PmL[((((size_t)s * NH + h) * NQT + qb) << 6) + er];
        ms[s] = p.x; ls[s] = p.y;
        m = fmaxf(m, p.x);
    }
    float L = 0.f, Ws[4];
    for (int s = 0; s < SPLITS; ++s) { Ws[s] = __expf(ms[s] - m); L += ls[s] * Ws[s]; }
    const float inv = 1.f / L;

    float o[16];
    #pragma unroll
    for (int j = 0; j < 16; ++j) o[j] = 0.f;
    for (int s = 0; s < SPLITS; ++s) {
        const float* src = Pacc + ((((((size_t)s * NH + h) * NQT + qb) << 6) + er) << 6) + (eu << 4);
        const float wgt = Ws[s];
        #pragma unroll
        for (int c = 0; c < 4; ++c) {
            const float4 f = *(const float4*)(src + c * 4);
            o[c * 4 + 0] += wgt * f.x;
            o[c * 4 + 1] += wgt * f.y;
            o[c * 4 + 2] += wgt * f.z;
            o[c * 4 + 3] += wgt * f.w;
        }
    }
    u16x8 h0, h1, l0v, l1v;
    #pragma unroll
    for (int j = 0; j < 8; ++j) { u16 hh, ll; split1(o[j] * inv, hh, ll); h0[j] = hh; l0v[j] = ll; }
    #pragma unroll
    for (int j = 0; j < 8; ++j) { u16 hh, ll; split1(o[8 + j] * inv, hh, ll); h1[j] = hh; l1v[j] = ll; }
    u16* dh = Ohi + (size_t)row * CDIM + h * HD + (eu << 4);
    u16* dl = Olo + (size_t)row * CDIM + h * HD + (eu << 4);
    *(u16x8*)dh = h0;  *(u16x8*)(dh + 8) = h1;
    *(u16x8*)dl = l0v; *(u16x8*)(dl + 8) = l1v;
}

// ---------------- Kernel 3: output projection via MFMA hi/lo ----------------
__global__ __launch_bounds__(256)
void proj_mfma(const u16* __restrict__ Ahi, const u16* __restrict__ Alo,
               const u16* __restrict__ Whi, const u16* __restrict__ Wlo,
               const float* __restrict__ bp, float* __restrict__ out)
{
    __shared__ __align__(16) u16 Ah[64][64], Al[64][64], Bh[64][64], Bl[64][64];

    const int rb = blockIdx.x;
    const int colbase = blockIdx.y * 64;
    const int tid = threadIdx.x;
    const int w = tid >> 6, l = tid & 63;
    const int lr = l & 15, lg = l >> 4;

    const int srow = tid >> 2, sch = (tid & 3) << 4;
    int arow = rb * 64 + srow;
    if (arow >= N_TOK) arow = N_TOK - 1;
    const size_t abase = (size_t)arow * CDIM + sch;
    const size_t bbase = (size_t)(colbase + srow) * CDIM + sch;

    f32x4 acc[4];
    #pragma unroll
    for (int i = 0; i < 4; ++i) acc[i] = (f32x4){0.f, 0.f, 0.f, 0.f};

    const int sw = (srow & 7) << 3;
    const int swf = (lr & 7) << 3;

    for (int k0 = 0; k0 < CDIM; k0 += 64) {
        const u16x8 a0h = *(const u16x8*)(Ahi + abase + k0);
        const u16x8 a1h = *(const u16x8*)(Ahi + abase + k0 + 8);
        const u16x8 a0l = *(const u16x8*)(Alo + abase + k0);
        const u16x8 a1l = *(const u16x8*)(Alo + abase + k0 + 8);
        const u16x8 b0h = *(const u16x8*)(Whi + bbase + k0);
        const u16x8 b1h = *(const u16x8*)(Whi + bbase + k0 + 8);
        const u16x8 b0l = *(const u16x8*)(Wlo + bbase + k0);
        const u16x8 b1l = *(const u16x8*)(Wlo + bbase + k0 + 8);
        __syncthreads();
        *(u16x8*)&Ah[srow][(sch + 0) ^ sw] = a0h;
        *(u16x8*)&Ah[srow][(sch + 8) ^ sw] = a1h;
        *(u16x8*)&Al[srow][(sch + 0) ^ sw] = a0l;
        *(u16x8*)&Al[srow][(sch + 8) ^ sw] = a1l;
        *(u16x8*)&Bh[srow][(sch + 0) ^ sw] = b0h;
        *(u16x8*)&Bh[srow][(sch + 8) ^ sw] = b1h;
        *(u16x8*)&Bl[srow][(sch + 0) ^ sw] = b0l;
        *(u16x8*)&Bl[srow][(sch + 8) ^ sw] = b1l;
        __syncthreads();
        #pragma unroll
        for (int ks = 0; ks < 2; ++ks) {
            const int koff = (ks * 32 + lg * 8) ^ swf;
            const bf16x8 ah_ = *(const bf16x8*)&Ah[w * 16 + lr][koff];
            const bf16x8 al_ = *(const bf16x8*)&Al[w * 16 + lr][koff];
            #pragma unroll
            for (int cbk = 0; cbk < 4; ++cbk) {
                const bf16x8 bh_ = *(const bf16x8*)&Bh[cbk * 16 + lr][koff];
                const bf16x8 bl_ = *(const bf16x8*)&Bl[cbk * 16 + lr][koff];
                acc[cbk] = __builtin_amdgcn_mfma_f32_16x16x32_bf16(ah_, bh_, acc[cbk], 0, 0, 0);
                acc[cbk] = __builtin_amdgcn_mfma_f32_16x16x32_bf16(ah_, bl_, acc[cbk], 0, 0, 0);
                acc[cbk] = __builtin_amdgcn_mfma_f32_16x16x32_bf16(al_, bh_, acc[cbk], 0, 0, 0);
            }
        }
    }

    #pragma unroll
    for (int cbk = 0; cbk < 4; ++cbk) {
        const float bb = bp[colbase + cbk * 16 + lr];
        #pragma unroll
        for (int r = 0; r < 4; ++r) {
            const int row = rb * 64 + w * 16 + lg * 4 + r;
            if (row < N_TOK)
                out[(size_t)row * CDIM + colbase + cbk * 16 + lr] = acc[cbk][r] + bb;
        }
    }
}

extern "C" void kernel_launch(void* const* d_in, const int* in_sizes, int n_in,
                              void* d_out, int out_size, void* d_ws, size_t ws_size,
                              hipStream_t stream)
{
    const float* q_tokens = (const float*)d_in[0];
    const float* t_tokens = (const float*)d_in[1];
    const float* pos2d    = (const float*)d_in[2];
    const float* tposes   = (const float*)d_in[3];
    const float* Wqkv     = (const float*)d_in[4];
    const float* bqkv     = (const float*)d_in[5];
    const float* Wproj    = (const float*)d_in[6];
    const float* bproj    = (const float*)d_in[7];
    float* out = (float*)d_out;

    const size_t PQ = (size_t)NH * N_TOK * HD;
    const size_t PV_ = (size_t)NH * HD * NVP;
    const size_t PX = (size_t)N_TOK * CDIM;
    const size_t PW = (size_t)QKV_COLS * CDIM;

    u16* base = (u16*)d_ws;
    u16* Qhi  = base;
    u16* Qlo  = Qhi + PQ;
    u16* Khi  = Qlo + PQ;
    u16* Klo  = Khi + PQ;
    u16* Vthi = Klo + PQ;
    u16* XOhi = Vthi + PV_;
    u16* XOlo = XOhi + PX;
    u16* WThi = XOlo + PX;
    u16* WTlo = WThi + PW;
    u16* planes_end = WTlo + PW;

    const size_t planes_bytes = (size_t)(planes_end - base) * sizeof(u16);
    const size_t accElems = (size_t)NH * NQT * 64 * 64;
    const size_t mlElems  = (size_t)NH * NQT * 64;
    const size_t per_shard = accElems * 4 + mlElems * 8;

    int SPLITS = 1;
    for (int cand = 4; cand >= 2; --cand) {
        if (planes_bytes + (size_t)cand * per_shard <= ws_size) { SPLITS = cand; break; }
    }
    float* Pacc = (float*)((char*)d_ws + planes_bytes);
    float2* PmL = (float2*)(Pacc + (size_t)SPLITS * accElems);
    const int TS = (NQT + SPLITS - 1) / SPLITS;

    conv_x<<<dim3((N_TOK * CDIM / 4 + 255) / 256), 256, 0, stream>>>(q_tokens, t_tokens, XOhi, XOlo);
    conv_wT<<<dim3(CDIM / 64, QKV_COLS / 64), 256, 0, stream>>>(Wqkv, QKV_COLS, WThi, WTlo);
    hipMemsetAsync(Vthi, 0, PV_ * sizeof(u16), stream);

    dim3 g1((N_TOK + 127) / 128, 36);
    qkv_mfma<<<g1, 256, 0, stream>>>(XOhi, XOlo, WThi, WTlo, bqkv, pos2d, tposes,
                                     Qhi, Qlo, Khi, Klo, Vthi);

    conv_wT<<<dim3(CDIM / 64, CDIM / 64), 256, 0, stream>>>(Wproj, CDIM, WThi, WTlo);

    dim3 g2(NQT, NH, SPLITS);
    attn_shard<<<g2, 256, 0, stream>>>(Qhi, Qlo, Khi, Klo, Vthi, Pacc, PmL, TS, SPLITS);

    dim3 g2b(NQT, NH);
    attn_combine<<<g2b, 256, 0, stream>>>(Pacc, PmL, XOhi, XOlo, SPLITS);

    dim3 g3((N_TOK + 63) / 64, CDIM / 64);
    proj_mfma<<<g3, 256, 0, stream>>>(XOhi, XOlo, WThi, WTlo, bproj, out);
}

// Round 11
// 202.179 us; speedup vs baseline: 1.3644x; 1.0195x over previous
//
#include <hip/hip_runtime.h>
#include <hip/hip_bf16.h>
#include <hip/hip_fp16.h>
#include <math.h>

#define N_TOK 2884
#define HW_IMG 576
#define NT_TOK 577
#define CDIM 768
#define NH 12
#define HD 64
#define QKV_COLS 2304
#define NVP 2944   // padded token stride for V^T plane
#define NQT 46     // number of 64-row q tiles (attention)
#define LOG2E 1.44269504088896340736f

typedef float f32x4 __attribute__((ext_vector_type(4)));
typedef short bf16x8 __attribute__((ext_vector_type(8)));
typedef _Float16 f16x8 __attribute__((ext_vector_type(8)));
typedef unsigned short u16;
typedef unsigned short u16x8 __attribute__((ext_vector_type(8)));
typedef unsigned short u16x4 __attribute__((ext_vector_type(4)));

static __device__ __forceinline__ u16 f2bf(float f) {
    union { __hip_bfloat16 b; u16 u; } cv;
    cv.b = __float2bfloat16(f);
    return cv.u;
}
static __device__ __forceinline__ float bf2f(u16 h) {
    return __uint_as_float(((unsigned)h) << 16);
}
static __device__ __forceinline__ void split1(float f, u16& h, u16& l) {
    h = f2bf(f);
    l = f2bf(f - bf2f(h));
}
static __device__ __forceinline__ f16x8 as_f16x8(u16x8 u) {
    union { u16x8 u; f16x8 h; } c; c.u = u; return c.h;
}

// ---------------- conv_x ----------------
__global__ __launch_bounds__(256)
void conv_x(const float* __restrict__ q, const float* __restrict__ t,
            u16* __restrict__ Xhi, u16* __restrict__ Xlo)
{
    const int i = (blockIdx.x * 256 + threadIdx.x) * 4;
    const int SPLIT = HW_IMG * CDIM;
    const float4 v = (i < SPLIT) ? *(const float4*)(q + i) : *(const float4*)(t + (i - SPLIT));
    u16x4 h, l;
    u16 hh, ll;
    split1(v.x, hh, ll); h[0] = hh; l[0] = ll;
    split1(v.y, hh, ll); h[1] = hh; l[1] = ll;
    split1(v.z, hh, ll); h[2] = hh; l[2] = ll;
    split1(v.w, hh, ll); h[3] = hh; l[3] = ll;
    *(u16x4*)(Xhi + i) = h;
    *(u16x4*)(Xlo + i) = l;
}

// ---------------- conv_wT ----------------
__global__ __launch_bounds__(256)
void conv_wT(const float* __restrict__ W, int ncols,
             u16* __restrict__ Thi, u16* __restrict__ Tlo)
{
    __shared__ float T[64][65];
    const int k0 = blockIdx.x * 64;
    const int n0 = blockIdx.y * 64;
    const int tid = threadIdx.x;
    {
        const int kr = tid >> 2, nch = (tid & 3) << 4;
        const float* src = W + (size_t)(k0 + kr) * ncols + n0 + nch;
        #pragma unroll
        for (int c = 0; c < 4; ++c) {
            const float4 f = *(const float4*)(src + c * 4);
            T[kr][nch + c * 4 + 0] = f.x;
            T[kr][nch + c * 4 + 1] = f.y;
            T[kr][nch + c * 4 + 2] = f.z;
            T[kr][nch + c * 4 + 3] = f.w;
        }
    }
    __syncthreads();
    const int nr = tid >> 2, kch = (tid & 3) << 4;
    u16x8 h0, h1, l0v, l1v;
    #pragma unroll
    for (int j = 0; j < 8; ++j) { u16 hh, ll; split1(T[kch + j][nr], hh, ll); h0[j] = hh; l0v[j] = ll; }
    #pragma unroll
    for (int j = 0; j < 8; ++j) { u16 hh, ll; split1(T[kch + 8 + j][nr], hh, ll); h1[j] = hh; l1v[j] = ll; }
    const size_t dst = (size_t)(n0 + nr) * CDIM + k0 + kch;
    *(u16x8*)(Thi + dst) = h0;     *(u16x8*)(Thi + dst + 8) = h1;
    *(u16x8*)(Tlo + dst) = l0v;    *(u16x8*)(Tlo + dst + 8) = l1v;
}

// ---------------- Kernel 1: QKV via MFMA hi/lo, 128x64 tile ----------------
// Q planes pre-scaled by (1/8)*log2(e): attention softmax runs in exp2 domain.
// V^T plane single fp16; pad tokens zero-filled here (no memset dispatch).
__global__ __launch_bounds__(256, 3)
void qkv_mfma(const u16* __restrict__ Xhi, const u16* __restrict__ Xlo,
              const u16* __restrict__ Whi, const u16* __restrict__ Wlo,
              const float* __restrict__ bqkv,
              const float* __restrict__ pos2d, const float* __restrict__ tposes,
              u16* __restrict__ Qhi, u16* __restrict__ Qlo,
              u16* __restrict__ Khi, u16* __restrict__ Klo,
              u16* __restrict__ Vthi)
{
    __shared__ __align__(16) char smem[49152];
    u16 (*Ah)[64] = (u16(*)[64])(smem);
    u16 (*Al)[64] = (u16(*)[64])(smem + 16384);
    u16 (*Bh)[64] = (u16(*)[64])(smem + 32768);
    u16 (*Bl)[64] = (u16(*)[64])(smem + 40960);
    float (*Ct)[65] = (float(*)[65])(smem);

    const int rb = blockIdx.x;
    const int cb = blockIdx.y;
    const int which = cb / NH;
    const int h = cb - which * NH;
    const int colbase = cb * 64;
    const int tid = threadIdx.x;
    const int w = tid >> 6, l = tid & 63;
    const int lr = l & 15, lg = l >> 4;

    const int sa_r = tid >> 1;
    const int sa_c = (tid & 1) << 5;
    int arow = rb * 128 + sa_r;
    if (arow >= N_TOK) arow = N_TOK - 1;
    const size_t abase = (size_t)arow * CDIM + sa_c;
    const int swa_ = (sa_r & 7) << 3;
    const int sb_r = tid >> 2;
    const int sb_c = (tid & 3) << 4;
    const size_t bbase = (size_t)(colbase + sb_r) * CDIM + sb_c;
    const int swb_ = (sb_r & 7) << 3;

    const int swf = (lr & 7) << 3;

    f32x4 acc[2][4];
    #pragma unroll
    for (int rf = 0; rf < 2; ++rf)
        #pragma unroll
        for (int i = 0; i < 4; ++i) acc[rf][i] = (f32x4){0.f, 0.f, 0.f, 0.f};

    for (int k0 = 0; k0 < CDIM; k0 += 64) {
        u16x8 a_h[4], a_l[4], b_h[2], b_l[2];
        #pragma unroll
        for (int c = 0; c < 4; ++c) {
            a_h[c] = *(const u16x8*)(Xhi + abase + k0 + c * 8);
            a_l[c] = *(const u16x8*)(Xlo + abase + k0 + c * 8);
        }
        #pragma unroll
        for (int c = 0; c < 2; ++c) {
            b_h[c] = *(const u16x8*)(Whi + bbase + k0 + c * 8);
            b_l[c] = *(const u16x8*)(Wlo + bbase + k0 + c * 8);
        }
        __syncthreads();
        #pragma unroll
        for (int c = 0; c < 4; ++c) {
            *(u16x8*)&Ah[sa_r][(sa_c + c * 8) ^ swa_] = a_h[c];
            *(u16x8*)&Al[sa_r][(sa_c + c * 8) ^ swa_] = a_l[c];
        }
        #pragma unroll
        for (int c = 0; c < 2; ++c) {
            *(u16x8*)&Bh[sb_r][(sb_c + c * 8) ^ swb_] = b_h[c];
            *(u16x8*)&Bl[sb_r][(sb_c + c * 8) ^ swb_] = b_l[c];
        }
        __syncthreads();
        #pragma unroll
        for (int ks = 0; ks < 2; ++ks) {
            const int koff = (ks * 32 + lg * 8) ^ swf;
            const bf16x8 ah0 = *(const bf16x8*)&Ah[w * 32 + lr][koff];
            const bf16x8 al0 = *(const bf16x8*)&Al[w * 32 + lr][koff];
            const bf16x8 ah1 = *(const bf16x8*)&Ah[w * 32 + 16 + lr][koff];
            const bf16x8 al1 = *(const bf16x8*)&Al[w * 32 + 16 + lr][koff];
            #pragma unroll
            for (int cbk = 0; cbk < 4; ++cbk) {
                const bf16x8 bh_ = *(const bf16x8*)&Bh[cbk * 16 + lr][koff];
                const bf16x8 bl_ = *(const bf16x8*)&Bl[cbk * 16 + lr][koff];
                acc[0][cbk] = __builtin_amdgcn_mfma_f32_16x16x32_bf16(ah0, bh_, acc[0][cbk], 0, 0, 0);
                acc[0][cbk] = __builtin_amdgcn_mfma_f32_16x16x32_bf16(ah0, bl_, acc[0][cbk], 0, 0, 0);
                acc[0][cbk] = __builtin_amdgcn_mfma_f32_16x16x32_bf16(al0, bh_, acc[0][cbk], 0, 0, 0);
                acc[1][cbk] = __builtin_amdgcn_mfma_f32_16x16x32_bf16(ah1, bh_, acc[1][cbk], 0, 0, 0);
                acc[1][cbk] = __builtin_amdgcn_mfma_f32_16x16x32_bf16(ah1, bl_, acc[1][cbk], 0, 0, 0);
                acc[1][cbk] = __builtin_amdgcn_mfma_f32_16x16x32_bf16(al1, bh_, acc[1][cbk], 0, 0, 0);
            }
        }
    }

    __syncthreads();
    #pragma unroll
    for (int rf = 0; rf < 2; ++rf)
        #pragma unroll
        for (int cbk = 0; cbk < 4; ++cbk)
            #pragma unroll
            for (int r = 0; r < 4; ++r)
                Ct[w * 32 + rf * 16 + lg * 4 + r][cbk * 16 + lr] =
                    acc[rf][cbk][r] + bqkv[colbase + cbk * 16 + lr];
    __syncthreads();

    if (which < 2) {
        #pragma unroll
        for (int it = 0; it < 2; ++it) {
            const int item = it * 256 + tid;
            const int er = item >> 2;
            const int eu = item & 3;
            const int n = rb * 128 + er;
            if (n < N_TOK) {
                float outv[16];
                const bool is_img = (n < HW_IMG);
                int ts = 0, tj = 0;
                if (!is_img) { const int m = n - HW_IMG; ts = m / NT_TOK; tj = m - ts * NT_TOK; }

                if (is_img) {
                    const float p = (eu < 2) ? pos2d[2 * n] : pos2d[2 * n + 1];
                    const bool lowhalf = ((eu & 1) == 0);
                    #pragma unroll
                    for (int dd = 0; dd < 16; ++dd) {
                        const int d = (eu << 4) + dd;
                        float sv, cv;
                        sincosf(p * expf((float)dd * -0.28782313662425574f), &sv, &cv);
                        const float rot = lowhalf ? -Ct[er][d + 16] : Ct[er][d - 16];
                        outv[dd] = Ct[er][d] * cv + rot * sv;
                    }
                } else if (tj < HW_IMG) {
                    #pragma unroll
                    for (int dd = 0; dd < 16; ++dd) {
                        const int d = (eu << 4) + dd;
                        float val = Ct[er][d];
                        if (d < 30) {
                            const int g = d / 3;
                            const float* R = tposes + ts * 16 + (d - g * 3) * 4;
                            val = R[0] * Ct[er][g * 3] + R[1] * Ct[er][g * 3 + 1] + R[2] * Ct[er][g * 3 + 2];
                        }
                        outv[dd] = val;
                    }
                } else {
                    #pragma unroll
                    for (int dd = 0; dd < 16; ++dd) outv[dd] = Ct[er][(eu << 4) + dd];
                }

                // Q: 1/8 * log2(e) so attention softmax runs in exp2 domain
                const float scale = (which == 0) ? (0.125f * LOG2E) : 1.0f;
                u16x8 h0, h1, l0v, l1v;
                #pragma unroll
                for (int j = 0; j < 8; ++j) { u16 hh, ll; split1(outv[j] * scale, hh, ll); h0[j] = hh; l0v[j] = ll; }
                #pragma unroll
                for (int j = 0; j < 8; ++j) { u16 hh, ll; split1(outv[8 + j] * scale, hh, ll); h1[j] = hh; l1v[j] = ll; }
                u16* dh = (which == 0 ? Qhi : Khi) + ((size_t)h * N_TOK + n) * HD + (eu << 4);
                u16* dl = (which == 0 ? Qlo : Klo) + ((size_t)h * N_TOK + n) * HD + (eu << 4);
                *(u16x8*)dh = h0;  *(u16x8*)(dh + 8) = h1;
                *(u16x8*)dl = l0v; *(u16x8*)(dl + 8) = l1v;
            }
        }
    } else {
        // V: single fp16, transposed plane [h][d][token]; pad tokens zero-filled
        #pragma unroll
        for (int it = 0; it < 2; ++it) {
            const int item = it * 256 + tid;
            const int vd_ = item >> 3;
            const int vch = (item & 7) << 4;
            const int tokbase = rb * 128 + vch;
            u16 th[16];
            #pragma unroll
            for (int j = 0; j < 16; ++j)
                th[j] = (tokbase + j < N_TOK)
                      ? __half_as_ushort(__float2half(Ct[vch + j][vd_]))
                      : (u16)0;
            u16* dh = Vthi + (size_t)(h * HD + vd_) * NVP + tokbase;
            *(u16x8*)dh = *(u16x8*)&th[0];
            *(u16x8*)(dh + 8) = *(u16x8*)&th[8];
        }
    }
}

// ---------------- Kernel 2: split-K flash attention; QK bf16 hi/lo, PV single fp16 ----------------
// exp2-domain softmax (Q pre-scaled by log2e/8), 64 q-rows/block, reg-prefetch,
// 2 barriers/tile, wave-private P, exact defer-max skip. LDS 32 KB.
__global__ __launch_bounds__(256, 3)
void attn_shard(const u16* __restrict__ Qhi, const u16* __restrict__ Qlo,
                const u16* __restrict__ Khi, const u16* __restrict__ Klo,
                const u16* __restrict__ Vthi,
                float* __restrict__ Pacc, float2* __restrict__ PmL,
                int TS, int SPLITS)
{
    __shared__ __align__(16) u16 Kh_s[64][64], Kl_s[64][64];   // bf16 hi/lo
    __shared__ __align__(16) u16 Vh_s[64][64];                 // fp16 single
    __shared__ __align__(16) u16 P2[64][64];                   // fp16 P (wave-private rows)

    int qb, head, sh;
    {
        const int flat = blockIdx.x + NQT * (blockIdx.y + NH * blockIdx.z);
        if (SPLITS == 4) {
            const int grp = flat & 7;
            const int rest = flat >> 3;
            qb = rest % NQT;
            const int hs = grp + 8 * (rest / NQT);
            head = hs % NH;
            sh = hs / NH;
        } else {
            qb = blockIdx.x; head = blockIdx.y; sh = blockIdx.z;
        }
    }
    const int tid = threadIdx.x;
    const int w = tid >> 6, l = tid & 63;
    const int lr = l & 15, lg = l >> 4;

    const int kt_begin = sh * TS;
    const int kt_end = min(NQT, kt_begin + TS);

    bf16x8 qh_[2], ql_[2];
    {
        int row = qb * 64 + w * 16 + lr;
        if (row >= N_TOK) row = N_TOK - 1;
        const u16* qph = Qhi + ((size_t)head * N_TOK + row) * HD;
        const u16* qpl = Qlo + ((size_t)head * N_TOK + row) * HD;
        #pragma unroll
        for (int ks = 0; ks < 2; ++ks) {
            qh_[ks] = *(const bf16x8*)(qph + ks * 32 + lg * 8);
            ql_[ks] = *(const bf16x8*)(qpl + ks * 32 + lg * 8);
        }
    }

    float m0[4] = {-1e30f, -1e30f, -1e30f, -1e30f};
    float l0[4] = {0.f, 0.f, 0.f, 0.f};
    f32x4 acc[4];
    #pragma unroll
    for (int db = 0; db < 4; ++db) acc[db] = (f32x4){0.f, 0.f, 0.f, 0.f};

    const int skey = tid >> 2, sch = (tid & 3) << 4;
    const int vd_ = tid >> 2, vch = (tid & 3) << 4;
    const int swk = (skey & 7) << 3;
    const int swv = (vd_ & 7) << 3;
    const int swf = (lr & 7) << 3;
    const u16* KhH = Khi + (size_t)head * N_TOK * HD;
    const u16* KlH = Klo + (size_t)head * N_TOK * HD;
    const size_t vrowbase = (size_t)(head * HD + vd_) * NVP;

    u16x8 rk0h, rk1h, rk0l, rk1l, rv0h, rv1h;
    auto LOADT = [&](int kt) {
        const int kbase = kt << 6;
        int krow = kbase + skey;
        if (krow >= N_TOK) krow = N_TOK - 1;
        const u16* kph = KhH + (size_t)krow * HD + sch;
        const u16* kpl = KlH + (size_t)krow * HD + sch;
        rk0h = *(const u16x8*)kph;  rk1h = *(const u16x8*)(kph + 8);
        rk0l = *(const u16x8*)kpl;  rk1l = *(const u16x8*)(kpl + 8);
        const u16* vph = Vthi + vrowbase + kbase + vch;
        rv0h = *(const u16x8*)vph;  rv1h = *(const u16x8*)(vph + 8);
    };
    LOADT(kt_begin);

    for (int kt = kt_begin; kt < kt_end; ++kt) {
        const int kbase = kt << 6;

        __syncthreads();
        *(u16x8*)&Kh_s[skey][(sch + 0) ^ swk] = rk0h;
        *(u16x8*)&Kh_s[skey][(sch + 8) ^ swk] = rk1h;
        *(u16x8*)&Kl_s[skey][(sch + 0) ^ swk] = rk0l;
        *(u16x8*)&Kl_s[skey][(sch + 8) ^ swk] = rk1l;
        *(u16x8*)&Vh_s[vd_][(vch + 0) ^ swv] = rv0h;
        *(u16x8*)&Vh_s[vd_][(vch + 8) ^ swv] = rv1h;
        if (kt + 1 < kt_end) LOADT(kt + 1);
        __syncthreads();

        // ---- S' = log2e * Q K^T (bf16 hi/lo 3-product; log2e folded into Q) ----
        f32x4 s[4];
        __builtin_amdgcn_s_setprio(1);
        #pragma unroll
        for (int kb = 0; kb < 4; ++kb) {
            s[kb] = (f32x4){0.f, 0.f, 0.f, 0.f};
            const int key = kb * 16 + lr;
            #pragma unroll
            for (int ks = 0; ks < 2; ++ks) {
                const int koff = (ks * 32 + lg * 8) ^ swf;
                const bf16x8 bh = *(const bf16x8*)&Kh_s[key][koff];
                const bf16x8 bl = *(const bf16x8*)&Kl_s[key][koff];
                s[kb] = __builtin_amdgcn_mfma_f32_16x16x32_bf16(qh_[ks], bh, s[kb], 0, 0, 0);
                s[kb] = __builtin_amdgcn_mfma_f32_16x16x32_bf16(qh_[ks], bl, s[kb], 0, 0, 0);
                s[kb] = __builtin_amdgcn_mfma_f32_16x16x32_bf16(ql_[ks], bh, s[kb], 0, 0, 0);
            }
        }
        __builtin_amdgcn_s_setprio(0);

        if (kbase + 64 > N_TOK) {
            #pragma unroll
            for (int kb = 0; kb < 4; ++kb)
                if (kbase + kb * 16 + lr >= N_TOK) {
                    #pragma unroll
                    for (int r = 0; r < 4; ++r) s[kb][r] = -1e30f;
                }
        }

        // ---- online softmax (exp2 domain) with exact defer-max skip ----
        float mt[4];
        #pragma unroll
        for (int r = 0; r < 4; ++r)
            mt[r] = fmaxf(fmaxf(s[0][r], s[1][r]), fmaxf(s[2][r], s[3][r]));
        #pragma unroll
        for (int r = 0; r < 4; ++r) {
            mt[r] = fmaxf(mt[r], __shfl_xor(mt[r], 1));
            mt[r] = fmaxf(mt[r], __shfl_xor(mt[r], 2));
            mt[r] = fmaxf(mt[r], __shfl_xor(mt[r], 4));
            mt[r] = fmaxf(mt[r], __shfl_xor(mt[r], 8));
        }
        const bool newmax = __any((mt[0] > m0[0]) | (mt[1] > m0[1]) |
                                  (mt[2] > m0[2]) | (mt[3] > m0[3]));
        if (newmax) {
            float al[4];
            #pragma unroll
            for (int r = 0; r < 4; ++r) {
                const float mn = fmaxf(m0[r], mt[r]);
                al[r] = __builtin_amdgcn_exp2f(m0[r] - mn);
                m0[r] = mn;
            }
            #pragma unroll
            for (int r = 0; r < 4; ++r) l0[r] *= al[r];
            #pragma unroll
            for (int db = 0; db < 4; ++db)
                #pragma unroll
                for (int r = 0; r < 4; ++r) acc[db][r] *= al[r];
        }
        #pragma unroll
        for (int kb = 0; kb < 4; ++kb)
            #pragma unroll
            for (int r = 0; r < 4; ++r)
                s[kb][r] = __builtin_amdgcn_exp2f(s[kb][r] - m0[r]);
        #pragma unroll
        for (int r = 0; r < 4; ++r)
            l0[r] += s[0][r] + s[1][r] + s[2][r] + s[3][r];

        // ---- pack P fp16 -> wave-private LDS rows ----
        #pragma unroll
        for (int r = 0; r < 4; ++r) {
            const int rw = w * 16 + lg * 4 + r;
            const int swp = (rw & 7) << 3;
            #pragma unroll
            for (int kb = 0; kb < 4; ++kb)
                P2[rw][(kb * 16 + lr) ^ swp] = __half_as_ushort(__float2half(s[kb][r]));
        }

        // ---- PV (single fp16) ----
        const int arow = w * 16 + lr;
        const int swpa = (arow & 7) << 3;
        #pragma unroll
        for (int ks = 0; ks < 2; ++ks) {
            const int kb8 = ks * 32 + lg * 8;
            const f16x8 pa = as_f16x8(*(const u16x8*)&P2[arow][kb8 ^ swpa]);
            __builtin_amdgcn_s_setprio(1);
            #pragma unroll
            for (int db = 0; db < 4; ++db) {
                const int vr = db * 16 + lr;
                const f16x8 vh = as_f16x8(*(const u16x8*)&Vh_s[vr][kb8 ^ swf]);
                acc[db] = __builtin_amdgcn_mfma_f32_16x16x32_f16(pa, vh, acc[db], 0, 0, 0);
            }
            __builtin_amdgcn_s_setprio(0);
        }
    }

    // ---- epilogue ----
    #pragma unroll
    for (int r = 0; r < 4; ++r) {
        l0[r] += __shfl_xor(l0[r], 1);
        l0[r] += __shfl_xor(l0[r], 2);
        l0[r] += __shfl_xor(l0[r], 4);
        l0[r] += __shfl_xor(l0[r], 8);
    }
    const size_t pb = (((size_t)sh * NH + head) * NQT + qb) << 6;
    float* pout = Pacc + (pb << 6);
    #pragma unroll
    for (int r = 0; r < 4; ++r) {
        const int lrow = w * 16 + lg * 4 + r;
        #pragma unroll
        for (int db = 0; db < 4; ++db)
            pout[(size_t)lrow * 64 + db * 16 + lr] = acc[db][r];
        if (lr == 0)
            PmL[pb + lrow] = make_float2(m0[r], l0[r]);   // m in log2 domain
    }
}

// ---------------- Kernel 2b: combine shards (exp2 domain weights) ----------------
__global__ __launch_bounds__(256)
void attn_combine(const float* __restrict__ Pacc, const float2* __restrict__ PmL,
                  u16* __restrict__ Ohi, u16* __restrict__ Olo, int SPLITS)
{
    const int qb = blockIdx.x, h = blockIdx.y;
    const int tid = threadIdx.x;
    const int er = tid >> 2, eu = tid & 3;
    const int row = qb * 64 + er;
    if (row >= N_TOK) return;

    float ms[4], ls[4];
    float m = -1e30f;
    for (int s = 0; s < SPLITS; ++s) {
        const float2 p = PmL[((((size_t)s * NH + h) * NQT + qb) << 6) + er];
        ms[s] = p.x; ls[s] = p.y;
        m = fmaxf(m, p.x);
    }
    float L = 0.f, Ws[4];
    for (int s = 0; s < SPLITS; ++s) { Ws[s] = __builtin_amdgcn_exp2f(ms[s] - m); L += ls[s] * Ws[s]; }
    const float inv = 1.f / L;

    float o[16];
    #pragma unroll
    for (int j = 0; j < 16; ++j) o[j] = 0.f;
    for (int s = 0; s < SPLITS; ++s) {
        const float* src = Pacc + ((((((size_t)s * NH + h) * NQT + qb) << 6) + er) << 6) + (eu << 4);
        const float wgt = Ws[s];
        #pragma unroll
        for (int c = 0; c < 4; ++c) {
            const float4 f = *(const float4*)(src + c * 4);
            o[c * 4 + 0] += wgt * f.x;
            o[c * 4 + 1] += wgt * f.y;
            o[c * 4 + 2] += wgt * f.z;
            o[c * 4 + 3] += wgt * f.w;
        }
    }
    u16x8 h0, h1, l0v, l1v;
    #pragma unroll
    for (int j = 0; j < 8; ++j) { u16 hh, ll; split1(o[j] * inv, hh, ll); h0[j] = hh; l0v[j] = ll; }
    #pragma unroll
    for (int j = 0; j < 8; ++j) { u16 hh, ll; split1(o[8 + j] * inv, hh, ll); h1[j] = hh; l1v[j] = ll; }
    u16* dh = Ohi + (size_t)row * CDIM + h * HD + (eu << 4);
    u16* dl = Olo + (size_t)row * CDIM + h * HD + (eu << 4);
    *(u16x8*)dh = h0;  *(u16x8*)(dh + 8) = h1;
    *(u16x8*)dl = l0v; *(u16x8*)(dl + 8) = l1v;
}

// ---------------- Kernel 3: output projection via MFMA hi/lo ----------------
__global__ __launch_bounds__(256)
void proj_mfma(const u16* __restrict__ Ahi, const u16* __restrict__ Alo,
               const u16* __restrict__ Whi, const u16* __restrict__ Wlo,
               const float* __restrict__ bp, float* __restrict__ out)
{
    __shared__ __align__(16) u16 Ah[64][64], Al[64][64], Bh[64][64], Bl[64][64];

    const int rb = blockIdx.x;
    const int colbase = blockIdx.y * 64;
    const int tid = threadIdx.x;
    const int w = tid >> 6, l = tid & 63;
    const int lr = l & 15, lg = l >> 4;

    const int srow = tid >> 2, sch = (tid & 3) << 4;
    int arow = rb * 64 + srow;
    if (arow >= N_TOK) arow = N_TOK - 1;
    const size_t abase = (size_t)arow * CDIM + sch;
    const size_t bbase = (size_t)(colbase + srow) * CDIM + sch;

    f32x4 acc[4];
    #pragma unroll
    for (int i = 0; i < 4; ++i) acc[i] = (f32x4){0.f, 0.f, 0.f, 0.f};

    const int sw = (srow & 7) << 3;
    const int swf = (lr & 7) << 3;

    for (int k0 = 0; k0 < CDIM; k0 += 64) {
        const u16x8 a0h = *(const u16x8*)(Ahi + abase + k0);
        const u16x8 a1h = *(const u16x8*)(Ahi + abase + k0 + 8);
        const u16x8 a0l = *(const u16x8*)(Alo + abase + k0);
        const u16x8 a1l = *(const u16x8*)(Alo + abase + k0 + 8);
        const u16x8 b0h = *(const u16x8*)(Whi + bbase + k0);
        const u16x8 b1h = *(const u16x8*)(Whi + bbase + k0 + 8);
        const u16x8 b0l = *(const u16x8*)(Wlo + bbase + k0);
        const u16x8 b1l = *(const u16x8*)(Wlo + bbase + k0 + 8);
        __syncthreads();
        *(u16x8*)&Ah[srow][(sch + 0) ^ sw] = a0h;
        *(u16x8*)&Ah[srow][(sch + 8) ^ sw] = a1h;
        *(u16x8*)&Al[srow][(sch + 0) ^ sw] = a0l;
        *(u16x8*)&Al[srow][(sch + 8) ^ sw] = a1l;
        *(u16x8*)&Bh[srow][(sch + 0) ^ sw] = b0h;
        *(u16x8*)&Bh[srow][(sch + 8) ^ sw] = b1h;
        *(u16x8*)&Bl[srow][(sch + 0) ^ sw] = b0l;
        *(u16x8*)&Bl[srow][(sch + 8) ^ sw] = b1l;
        __syncthreads();
        #pragma unroll
        for (int ks = 0; ks < 2; ++ks) {
            const int koff = (ks * 32 + lg * 8) ^ swf;
            const bf16x8 ah_ = *(const bf16x8*)&Ah[w * 16 + lr][koff];
            const bf16x8 al_ = *(const bf16x8*)&Al[w * 16 + lr][koff];
            #pragma unroll
            for (int cbk = 0; cbk < 4; ++cbk) {
                const bf16x8 bh_ = *(const bf16x8*)&Bh[cbk * 16 + lr][koff];
                const bf16x8 bl_ = *(const bf16x8*)&Bl[cbk * 16 + lr][koff];
                acc[cbk] = __builtin_amdgcn_mfma_f32_16x16x32_bf16(ah_, bh_, acc[cbk], 0, 0, 0);
                acc[cbk] = __builtin_amdgcn_mfma_f32_16x16x32_bf16(ah_, bl_, acc[cbk], 0, 0, 0);
                acc[cbk] = __builtin_amdgcn_mfma_f32_16x16x32_bf16(al_, bh_, acc[cbk], 0, 0, 0);
            }
        }
    }

    #pragma unroll
    for (int cbk = 0; cbk < 4; ++cbk) {
        const float bb = bp[colbase + cbk * 16 + lr];
        #pragma unroll
        for (int r = 0; r < 4; ++r) {
            const int row = rb * 64 + w * 16 + lg * 4 + r;
            if (row < N_TOK)
                out[(size_t)row * CDIM + colbase + cbk * 16 + lr] = acc[cbk][r] + bb;
        }
    }
}

extern "C" void kernel_launch(void* const* d_in, const int* in_sizes, int n_in,
                              void* d_out, int out_size, void* d_ws, size_t ws_size,
                              hipStream_t stream)
{
    const float* q_tokens = (const float*)d_in[0];
    const float* t_tokens = (const float*)d_in[1];
    const float* pos2d    = (const float*)d_in[2];
    const float* tposes   = (const float*)d_in[3];
    const float* Wqkv     = (const float*)d_in[4];
    const float* bqkv     = (const float*)d_in[5];
    const float* Wproj    = (const float*)d_in[6];
    const float* bproj    = (const float*)d_in[7];
    float* out = (float*)d_out;

    const size_t PQ = (size_t)NH * N_TOK * HD;
    const size_t PV_ = (size_t)NH * HD * NVP;
    const size_t PX = (size_t)N_TOK * CDIM;
    const size_t PW = (size_t)QKV_COLS * CDIM;

    u16* base = (u16*)d_ws;
    u16* Qhi  = base;
    u16* Qlo  = Qhi + PQ;
    u16* Khi  = Qlo + PQ;
    u16* Klo  = Khi + PQ;
    u16* Vthi = Klo + PQ;
    u16* XOhi = Vthi + PV_;
    u16* XOlo = XOhi + PX;
    u16* WThi = XOlo + PX;
    u16* WTlo = WThi + PW;
    u16* planes_end = WTlo + PW;

    const size_t planes_bytes = (size_t)(planes_end - base) * sizeof(u16);
    const size_t accElems = (size_t)NH * NQT * 64 * 64;
    const size_t mlElems  = (size_t)NH * NQT * 64;
    const size_t per_shard = accElems * 4 + mlElems * 8;

    int SPLITS = 1;
    for (int cand = 4; cand >= 2; --cand) {
        if (planes_bytes + (size_t)cand * per_shard <= ws_size) { SPLITS = cand; break; }
    }
    float* Pacc = (float*)((char*)d_ws + planes_bytes);
    float2* PmL = (float2*)(Pacc + (size_t)SPLITS * accElems);
    const int TS = (NQT + SPLITS - 1) / SPLITS;

    conv_x<<<dim3((N_TOK * CDIM / 4 + 255) / 256), 256, 0, stream>>>(q_tokens, t_tokens, XOhi, XOlo);
    conv_wT<<<dim3(CDIM / 64, QKV_COLS / 64), 256, 0, stream>>>(Wqkv, QKV_COLS, WThi, WTlo);

    dim3 g1((N_TOK + 127) / 128, 36);
    qkv_mfma<<<g1, 256, 0, stream>>>(XOhi, XOlo, WThi, WTlo, bqkv, pos2d, tposes,
                                     Qhi, Qlo, Khi, Klo, Vthi);

    conv_wT<<<dim3(CDIM / 64, CDIM / 64), 256, 0, stream>>>(Wproj, CDIM, WThi, WTlo);

    dim3 g2(NQT, NH, SPLITS);
    attn_shard<<<g2, 256, 0, stream>>>(Qhi, Qlo, Khi, Klo, Vthi, Pacc, PmL, TS, SPLITS);

    dim3 g2b(NQT, NH);
    attn_combine<<<g2b, 256, 0, stream>>>(Pacc, PmL, XOhi, XOlo, SPLITS);

    dim3 g3((N_TOK + 63) / 64, CDIM / 64);
    proj_mfma<<<g3, 256, 0, stream>>>(XOhi, XOlo, WThi, WTlo, bproj, out);
}